// Round 2
// baseline (310.554 us; speedup 1.0000x reference)
//
#include <hip/hip_runtime.h>
#include <hip/hip_fp16.h>
#include <cmath>

// Problem constants
#define BATCH   16
#define SEQ     2048
#define IN_DIM  57
#define D_MODEL 64
#define HEADDIM 32
#define D_STATE 32
#define OUT_DIM 6
#define D_INNER 128
#define NHEADS  4
#define D_CONV  4
#define D_XBC   192          // D_INNER + 2*D_STATE
#define D_XD    196          // conv channels (192) + dt (4)
#define D_IN_PROJ 324        // 2*D_INNER + 2*D_STATE + NHEADS
#define BL      (BATCH*SEQ)  // 32768

// Chunked scan config
#define NCHUNK  64
#define CLEN    (SEQ / NCHUNK)   // 32
#define GRID_SC 512              // 2 chunk-tasks per block; 2 blocks/CU -> all resident

// inproj tiling
#define RTILE   24
#define XPAD    60

// Workspace layout (floats). zb/xd/sbuf hold fp16 (2 halfs per float slot).
#define OFF_WF   ((size_t)0)
#define OFF_BF   ((size_t)18496)
#define OFF_WOC  ((size_t)18848)
#define OFF_G    ((size_t)19744)
#define OFF_P    ((size_t)21792)                    // 64*64 = 4096 floats
#define OFF_FLAG ((size_t)25888)                    // 8 words (barrier counters)
#define OFF_ZB   ((size_t)156960)                   // BL*128 halfs = BL*64 floats
#define OFF_XD   (OFF_ZB + (size_t)BL*64)           // BL*196 halfs = BL*98 floats
#define OFF_SB   (OFF_XD + (size_t)BL*98)           // 64*64*1024 halfs = 2.1M floats

// ---------------------------------------------------------------------------
// Kernel 1: Wf = W_lin@W_in ; bf = b_lin@W_in ; W_oc = W_out@W_cls.
// Also zeroes the G accumulator and barrier flags.
__global__ void fuse_w_kernel(const float* __restrict__ W_lin,
                              const float* __restrict__ b_lin,
                              const float* __restrict__ W_in,
                              const float* __restrict__ W_out,
                              const float* __restrict__ W_cls,
                              float* __restrict__ Wf, float* __restrict__ bf,
                              float* __restrict__ Woc, float* __restrict__ G,
                              unsigned* __restrict__ flags) {
    int idx = blockIdx.x * 256 + threadIdx.x;
    if (idx < BATCH * D_INNER) G[idx] = 0.f;
    if (idx < 8) flags[idx] = 0u;
    if (idx < 58 * D_IN_PROJ) {
        int r = idx / D_IN_PROJ;
        int j = idx - r * D_IN_PROJ;
        const float* v = (r < IN_DIM) ? (W_lin + r * D_MODEL) : b_lin;
        float acc = 0.f;
#pragma unroll 8
        for (int m = 0; m < D_MODEL; ++m) acc += v[m] * W_in[m * D_IN_PROJ + j];
        if (r < IN_DIM) Wf[r * D_IN_PROJ + j] = acc;
        else            bf[j] = acc;
    } else if (idx < 58 * D_IN_PROJ + D_INNER * OUT_DIM) {
        int idx2 = idx - 58 * D_IN_PROJ;
        int i = idx2 / OUT_DIM;
        int o = idx2 - i * OUT_DIM;
        float acc = 0.f;
#pragma unroll 8
        for (int j = 0; j < D_MODEL; ++j)
            acc += W_out[i * D_MODEL + j] * W_cls[j * OUT_DIM + o];
        Woc[i * OUT_DIM + o] = acc;
    }
}

// ---------------------------------------------------------------------------
// Kernel 2: LDS-staged in-projection. Block: 24 rows x 324 cols.
// Outputs quantized to fp16: z cols (0..127) -> zbh (stride 128 halfs),
// conv-in + dt cols -> xdh (stride 196 halfs).
__global__ __launch_bounds__(256) void inproj_kernel(
        const float* __restrict__ x,
        const float* __restrict__ Wf,
        const float* __restrict__ bf,
        __half* __restrict__ zbh,
        __half* __restrict__ xdh) {
    __shared__ float xs[RTILE][XPAD];
    int r0 = blockIdx.x * RTILE;
    for (int i = threadIdx.x; i < RTILE * IN_DIM; i += 256) {
        size_t g = (size_t)r0 * IN_DIM + i;
        float v = (g < (size_t)BL * IN_DIM) ? x[g] : 0.f;
        xs[i / IN_DIM][i % IN_DIM] = v;
    }
    __syncthreads();
    if (threadIdx.x >= 243) return;
    int rset = threadIdx.x / 81;
    int cg   = threadIdx.x - rset * 81;
    int j0   = cg * 4;
    float4 bias = *(const float4*)(bf + j0);
    float4 acc[8];
#pragma unroll
    for (int r = 0; r < 8; ++r) acc[r] = bias;
    const float* w = Wf + j0;
    const float* xrow = &xs[rset * 8][0];
#pragma unroll 2
    for (int kc = 0; kc < 14; ++kc) {
        int k = kc * 4;
        float4 wv0 = *(const float4*)(w + (size_t)(k + 0) * D_IN_PROJ);
        float4 wv1 = *(const float4*)(w + (size_t)(k + 1) * D_IN_PROJ);
        float4 wv2 = *(const float4*)(w + (size_t)(k + 2) * D_IN_PROJ);
        float4 wv3 = *(const float4*)(w + (size_t)(k + 3) * D_IN_PROJ);
#pragma unroll
        for (int r = 0; r < 8; ++r) {
            float4 xv = *(const float4*)(xrow + r * XPAD + k);
            acc[r].x += xv.x * wv0.x + xv.y * wv1.x + xv.z * wv2.x + xv.w * wv3.x;
            acc[r].y += xv.x * wv0.y + xv.y * wv1.y + xv.z * wv2.y + xv.w * wv3.y;
            acc[r].z += xv.x * wv0.z + xv.y * wv1.z + xv.z * wv2.z + xv.w * wv3.z;
            acc[r].w += xv.x * wv0.w + xv.y * wv1.w + xv.z * wv2.w + xv.w * wv3.w;
        }
    }
    {
        float4 wv = *(const float4*)(w + (size_t)56 * D_IN_PROJ);
#pragma unroll
        for (int r = 0; r < 8; ++r) {
            float xv = xrow[r * XPAD + 56];
            acc[r].x += xv * wv.x; acc[r].y += xv * wv.y;
            acc[r].z += xv * wv.z; acc[r].w += xv * wv.w;
        }
    }
#pragma unroll
    for (int r = 0; r < 8; ++r) {
        int row = r0 + rset * 8 + r;
        if (row < BL) {
            __half2 h01 = __floats2half2_rn(acc[r].x, acc[r].y);
            __half2 h23 = __floats2half2_rn(acc[r].z, acc[r].w);
            uint2 u;
            u.x = *(unsigned*)&h01;
            u.y = *(unsigned*)&h23;
            if (j0 < D_INNER)
                *(uint2*)(zbh + (size_t)row * D_INNER + j0) = u;
            else
                *(uint2*)(xdh + (size_t)row * D_XD + (j0 - D_INNER)) = u;
        }
    }
}

// ---------------------------------------------------------------------------
// Conv + dt prologue (fp16 xd input, fp32 compute).
__device__ __forceinline__ void conv_prologue(
        const __half* __restrict__ xdh,
        const float* __restrict__ conv_w, const float* __restrict__ conv_b,
        const float* __restrict__ dt_bias, const float* __restrict__ A_log,
        size_t rbase, int c, int tid,
        float (*xbt)[D_XBC], float (*ddl)[8]) {
    if (tid < D_XBC) {
        int ch = tid;
        float w0 = conv_w[ch*4+0], w1 = conv_w[ch*4+1];
        float w2 = conv_w[ch*4+2], w3 = conv_w[ch*4+3];
        float cb = conv_b[ch];
        const __half* src = xdh + rbase * D_XD + ch;
        float vm1 = 0.f, vm2 = 0.f, vm3 = 0.f;
        if (c > 0) {
            vm1 = __half2float(src[-(int)D_XD]);
            vm2 = __half2float(src[-2*(int)D_XD]);
            vm3 = __half2float(src[-3*(int)D_XD]);
        }
#pragma unroll
        for (int i = 0; i < CLEN; ++i) {
            float v0 = __half2float(src[(size_t)i * D_XD]);
            float a = cb + v0 * w3 + vm1 * w2 + vm2 * w1 + vm3 * w0;
            xbt[i][ch] = a / (1.f + expf(-a));   // SiLU
            vm3 = vm2; vm2 = vm1; vm1 = v0;
        }
    } else {
        int idx = tid - D_XBC;       // 0..63
        int h = idx >> 4;
        int i0 = idx & 15;
        float db = dt_bias[h];
        float nA = -expf(A_log[h]);
#pragma unroll
        for (int i = i0; i < CLEN; i += 16) {
            float v = __half2float(xdh[(rbase + i) * D_XD + 192 + h]) + db;
            float dtv = (v > 20.f) ? v : log1pf(expf(v));
            ddl[i][h * 2]     = dtv;
            ddl[i][h * 2 + 1] = expf(dtv * nA);
        }
    }
}

// ---------------------------------------------------------------------------
// Fused scan: phase1 (conv + unseeded scan, y_u/C/cumdec kept in LDS) ->
// device barrier -> phase2 (chunk-state combine, 128 blocks) -> device
// barrier -> phase3 (seed correction + gate + RMSNorm + G accumulate).
// Grid = 512 blocks x 64 KB LDS = exactly 2 blocks/CU -> all co-resident,
// so the atomic-counter spin barrier cannot deadlock.
__global__ __launch_bounds__(256) void scan_fused_kernel(
        const __half* __restrict__ xdh,
        const float* __restrict__ conv_w, const float* __restrict__ conv_b,
        const float* __restrict__ dt_bias, const float* __restrict__ A_log,
        const float* __restrict__ Dp, const __half* __restrict__ zbh,
        const float* __restrict__ norm_w,
        __half* __restrict__ sbuf, float* __restrict__ Pbuf,
        float* __restrict__ G, unsigned* __restrict__ flags) {
    __shared__ float xbt[CLEN][D_XBC];              // 24 KB (scratch per task)
    __shared__ float ddl[CLEN][8];                  // 1 KB  (scratch per task)
    __shared__ float ylds[2][CLEN][D_INNER];        // 32 KB (persists)
    __shared__ __align__(16) __half Cl[2][CLEN][D_STATE]; // 4 KB (persists)
    __shared__ float dcl[2][CLEN * 4];              // 1 KB (persists)
    __shared__ float red[4][D_INNER];               // 2 KB (scratch)
    int bid = blockIdx.x;
    int tid = threadIdx.x;
    int h = tid >> 6, lane = tid & 63;
    int p = lane >> 1, n0 = (lane & 1) * 16;
    float Dh = Dp[h];

    // ---- phase 1: two chunk-tasks per block ----
    for (int ti = 0; ti < 2; ++ti) {
        int t = bid + ti * GRID_SC;
        int b = t >> 6, c = t & (NCHUNK - 1);
        size_t rbase = (size_t)b * SEQ + (size_t)c * CLEN;
        conv_prologue(xdh, conv_w, conv_b, dt_bias, A_log, rbase, c, tid, xbt, ddl);
        __syncthreads();
        float4 s0 = make_float4(0.f,0.f,0.f,0.f), s1 = s0, s2 = s0, s3 = s0;
        float pacc = 1.f;
#pragma unroll 4
        for (int i = 0; i < CLEN; ++i) {
            float dtv = ddl[i][h * 2];
            float dec = ddl[i][h * 2 + 1];
            float xv = xbt[i][h * HEADDIM + p];
            const float* Bp = &xbt[i][D_INNER + n0];
            const float* Cp = &xbt[i][D_INNER + D_STATE + n0];
            float4 B0 = *(const float4*)(Bp + 0);
            float4 B1 = *(const float4*)(Bp + 4);
            float4 B2 = *(const float4*)(Bp + 8);
            float4 B3 = *(const float4*)(Bp + 12);
            float4 C0 = *(const float4*)(Cp + 0);
            float4 C1 = *(const float4*)(Cp + 4);
            float4 C2 = *(const float4*)(Cp + 8);
            float4 C3 = *(const float4*)(Cp + 12);
            float coef = dtv * xv;
            s0.x = s0.x*dec + coef*B0.x; s0.y = s0.y*dec + coef*B0.y;
            s0.z = s0.z*dec + coef*B0.z; s0.w = s0.w*dec + coef*B0.w;
            s1.x = s1.x*dec + coef*B1.x; s1.y = s1.y*dec + coef*B1.y;
            s1.z = s1.z*dec + coef*B1.z; s1.w = s1.w*dec + coef*B1.w;
            s2.x = s2.x*dec + coef*B2.x; s2.y = s2.y*dec + coef*B2.y;
            s2.z = s2.z*dec + coef*B2.z; s2.w = s2.w*dec + coef*B2.w;
            s3.x = s3.x*dec + coef*B3.x; s3.y = s3.y*dec + coef*B3.y;
            s3.z = s3.z*dec + coef*B3.z; s3.w = s3.w*dec + coef*B3.w;
            pacc *= dec;
            float part = s0.x*C0.x + s0.y*C0.y + s0.z*C0.z + s0.w*C0.w
                       + s1.x*C1.x + s1.y*C1.y + s1.z*C1.z + s1.w*C1.w
                       + s2.x*C2.x + s2.y*C2.y + s2.z*C2.z + s2.w*C2.w
                       + s3.x*C3.x + s3.y*C3.y + s3.z*C3.z + s3.w*C3.w;
            part += __shfl_xor(part, 1);
            if (lane == 0) dcl[ti][i * 4 + h] = pacc;
            if ((lane & 1) == 0)
                ylds[ti][i][h * HEADDIM + p] = part + Dh * xv;
        }
        int bh = b * NHEADS + h;
        __half2 hs[8];
        hs[0] = __floats2half2_rn(s0.x, s0.y); hs[1] = __floats2half2_rn(s0.z, s0.w);
        hs[2] = __floats2half2_rn(s1.x, s1.y); hs[3] = __floats2half2_rn(s1.z, s1.w);
        hs[4] = __floats2half2_rn(s2.x, s2.y); hs[5] = __floats2half2_rn(s2.z, s2.w);
        hs[6] = __floats2half2_rn(s3.x, s3.y); hs[7] = __floats2half2_rn(s3.z, s3.w);
        uint4* sp = (uint4*)(sbuf + ((size_t)bh * NCHUNK + c) * 1024) + lane * 2;
        sp[0] = *(uint4*)&hs[0];
        sp[1] = *(uint4*)&hs[4];
        if (lane == 0) Pbuf[bh * NCHUNK + c] = pacc;
        // save C rows (fp16) for the correction phase (xbt is reused next task)
        for (int idx2 = tid; idx2 < CLEN * 16; idx2 += 256) {
            int r = idx2 >> 4, n2 = (idx2 & 15) * 2;
            *((__half2*)&Cl[ti][r][n2]) =
                __floats2half2_rn(xbt[r][D_INNER + D_STATE + n2],
                                  xbt[r][D_INNER + D_STATE + n2 + 1]);
        }
        __syncthreads();
    }

    // ---- device barrier 1: all chunk states written ----
    if (tid == 0) {
        __threadfence();
        atomicAdd(&flags[0], 1u);
        while (__hip_atomic_load(&flags[0], __ATOMIC_ACQUIRE,
                                 __HIP_MEMORY_SCOPE_AGENT) < GRID_SC)
            __builtin_amdgcn_s_sleep(2);
    }
    __syncthreads();

    // ---- phase 2: combine chunk states (blocks 0..127) ----
    if (bid < 128) {
        int bh2 = bid >> 1, q = bid & 1;
        int idx = q * 256 + tid;     // 0..511
        unsigned* s32 = (unsigned*)sbuf;
        float rx = 0.f, ry = 0.f;
#pragma unroll 8
        for (int c = 0; c < NCHUNK; ++c) {
            size_t a = ((size_t)bh2 * NCHUNK + c) * 512 + idx;
            unsigned v = s32[a];
            float Pv = Pbuf[bh2 * NCHUNK + c];
            __half2 hv = *(__half2*)&v;
            float2 tt = __half22float2(hv);
            __half2 hr = __floats2half2_rn(rx, ry);
            s32[a] = *(unsigned*)&hr;
            rx = rx * Pv + tt.x;
            ry = ry * Pv + tt.y;
        }
        __threadfence();
    }
    __syncthreads();

    // ---- device barrier 2: all seeds written ----
    if (tid == 0) {
        __threadfence();
        atomicAdd(&flags[1], 1u);
        while (__hip_atomic_load(&flags[1], __ATOMIC_ACQUIRE,
                                 __HIP_MEMORY_SCOPE_AGENT) < GRID_SC)
            __builtin_amdgcn_s_sleep(2);
    }
    __syncthreads();

    // ---- phase 3a: seed correction y += cumdec * (C . seed) ----
    for (int ti = 0; ti < 2; ++ti) {
        int t = bid + ti * GRID_SC;
        int b = t >> 6, c = t & (NCHUNK - 1);
        int bh = b * NHEADS + h;
        const uint4* sp = (const uint4*)(sbuf + ((size_t)bh * NCHUNK + c) * 1024) + lane * 2;
        uint4 u0 = sp[0], u1 = sp[1];
        float4 s0, s1, s2, s3;
        {
            const __half2* hp0 = (const __half2*)&u0;
            const __half2* hp1 = (const __half2*)&u1;
            float2 f;
            f = __half22float2(hp0[0]); s0.x = f.x; s0.y = f.y;
            f = __half22float2(hp0[1]); s0.z = f.x; s0.w = f.y;
            f = __half22float2(hp0[2]); s1.x = f.x; s1.y = f.y;
            f = __half22float2(hp0[3]); s1.z = f.x; s1.w = f.y;
            f = __half22float2(hp1[0]); s2.x = f.x; s2.y = f.y;
            f = __half22float2(hp1[1]); s2.z = f.x; s2.w = f.y;
            f = __half22float2(hp1[2]); s3.x = f.x; s3.y = f.y;
            f = __half22float2(hp1[3]); s3.z = f.x; s3.w = f.y;
        }
#pragma unroll 4
        for (int i = 0; i < CLEN; ++i) {
            const uint4* cp = (const uint4*)&Cl[ti][i][n0];
            uint4 ua = cp[0], ub = cp[1];
            const __half2* cha = (const __half2*)&ua;
            const __half2* chb = (const __half2*)&ub;
            float2 f0 = __half22float2(cha[0]);
            float2 f1 = __half22float2(cha[1]);
            float2 f2 = __half22float2(cha[2]);
            float2 f3 = __half22float2(cha[3]);
            float2 f4 = __half22float2(chb[0]);
            float2 f5 = __half22float2(chb[1]);
            float2 f6 = __half22float2(chb[2]);
            float2 f7 = __half22float2(chb[3]);
            float part = s0.x*f0.x + s0.y*f0.y + s0.z*f1.x + s0.w*f1.y
                       + s1.x*f2.x + s1.y*f2.y + s1.z*f3.x + s1.w*f3.y
                       + s2.x*f4.x + s2.y*f4.y + s2.z*f5.x + s2.w*f5.y
                       + s3.x*f6.x + s3.y*f6.y + s3.z*f7.x + s3.w*f7.y;
            part += __shfl_xor(part, 1);
            if ((lane & 1) == 0)
                ylds[ti][i][h * HEADDIM + p] += dcl[ti][i * 4 + h] * part;
        }
    }
    __syncthreads();

    // ---- phase 3b: gate * silu(z) + RMSNorm + G accumulate ----
    for (int ti = 0; ti < 2; ++ti) {
        int t = bid + ti * GRID_SC;
        int b = t >> 6, c = t & (NCHUNK - 1);
        size_t rbase = (size_t)b * SEQ + (size_t)c * CLEN;
        float acc0 = 0.f, acc1 = 0.f;
        for (int r = h; r < CLEN; r += 4) {
            size_t bl = rbase + r;
            float2 yv = *(const float2*)(&ylds[ti][r][lane * 2]);
            float2 zv = __half22float2(*((const __half2*)(zbh + bl * D_INNER) + lane));
            float g0 = yv.x * (zv.x / (1.f + expf(-zv.x)));
            float g1 = yv.y * (zv.y / (1.f + expf(-zv.y)));
            float sq = g0 * g0 + g1 * g1;
#pragma unroll
            for (int m = 1; m < 64; m <<= 1) sq += __shfl_xor(sq, m);
            float rms = 1.0f / sqrtf(sq * (1.f / 128.f) + 1e-5f);
            acc0 += g0 * rms;
            acc1 += g1 * rms;
        }
        red[h][lane * 2]     = acc0;
        red[h][lane * 2 + 1] = acc1;
        __syncthreads();
        if (tid < D_INNER) {
            float sg = red[0][tid] + red[1][tid] + red[2][tid] + red[3][tid];
            atomicAdd(&G[b * D_INNER + tid], sg * norm_w[tid]);
        }
        __syncthreads();
    }
}

// ---------------------------------------------------------------------------
// Kernel 4: out[b][o] = b_cls[o] + (G[b] @ W_oc)[o] / SEQ
__global__ void head_kernel(const float* __restrict__ G,
                            const float* __restrict__ Woc,
                            const float* __restrict__ b_cls,
                            float* __restrict__ out) {
    int tid = threadIdx.x;
    if (tid >= BATCH * OUT_DIM) return;
    int b = tid / OUT_DIM, o = tid - b * OUT_DIM;
    float acc = 0.f;
#pragma unroll 8
    for (int i = 0; i < D_INNER; ++i)
        acc += G[b * D_INNER + i] * Woc[i * OUT_DIM + o];
    out[b * OUT_DIM + o] = acc * (1.f / (float)SEQ) + b_cls[o];
}

// ---------------------------------------------------------------------------
extern "C" void kernel_launch(void* const* d_in, const int* in_sizes, int n_in,
                              void* d_out, int out_size, void* d_ws, size_t ws_size,
                              hipStream_t stream) {
    const float* x       = (const float*)d_in[0];
    const float* W_lin   = (const float*)d_in[1];
    const float* b_lin   = (const float*)d_in[2];
    const float* W_in    = (const float*)d_in[3];
    const float* conv_w  = (const float*)d_in[4];
    const float* conv_b  = (const float*)d_in[5];
    const float* dt_bias = (const float*)d_in[6];
    const float* A_log   = (const float*)d_in[7];
    const float* Dp      = (const float*)d_in[8];
    const float* norm_w  = (const float*)d_in[9];
    const float* W_out   = (const float*)d_in[10];
    const float* W_cls   = (const float*)d_in[11];
    const float* b_cls   = (const float*)d_in[12];
    float* out = (float*)d_out;

    float* ws = (float*)d_ws;
    float* Wf      = ws + OFF_WF;
    float* bf      = ws + OFF_BF;
    float* Woc     = ws + OFF_WOC;
    float* G       = ws + OFF_G;
    float* Pbuf    = ws + OFF_P;
    unsigned* flags = (unsigned*)(ws + OFF_FLAG);
    __half* zbh  = (__half*)(ws + OFF_ZB);
    __half* xdh  = (__half*)(ws + OFF_XD);
    __half* sbuf = (__half*)(ws + OFF_SB);

    // 1) fused weight precompute (also zeroes G + barrier flags)
    fuse_w_kernel<<<(58 * D_IN_PROJ + D_INNER * OUT_DIM + 255) / 256, 256, 0, stream>>>(
        W_lin, b_lin, W_in, W_out, W_cls, Wf, bf, Woc, G, flags);

    // 2) in-projection (LDS-staged, 24 rows/block; fp16 z / xd outputs)
    inproj_kernel<<<(BL + RTILE - 1) / RTILE, 256, 0, stream>>>(x, Wf, bf, zbh, xdh);

    // 3) fully fused chunked selective scan (conv + scan + combine + gate +
    //    norm) with in-kernel device barriers; 512 blocks all co-resident.
    scan_fused_kernel<<<GRID_SC, 256, 0, stream>>>(
        xdh, conv_w, conv_b, dt_bias, A_log, Dp, zbh, norm_w, sbuf, Pbuf, G, flags);

    // 4) classifier head
    head_kernel<<<1, 128, 0, stream>>>(G, Woc, b_cls, out);
}

// Round 3
// 186.506 us; speedup vs baseline: 1.6651x; 1.6651x over previous
//
#include <hip/hip_runtime.h>
#include <hip/hip_fp16.h>
#include <cmath>

// Problem constants
#define BATCH   16
#define SEQ     2048
#define IN_DIM  57
#define D_MODEL 64
#define HEADDIM 32
#define D_STATE 32
#define OUT_DIM 6
#define D_INNER 128
#define NHEADS  4
#define D_CONV  4
#define D_XBC   192          // D_INNER + 2*D_STATE
#define D_XD    196          // conv channels (192) + dt (4)
#define D_IN_PROJ 324        // 2*D_INNER + 2*D_STATE + NHEADS
#define BL      (BATCH*SEQ)  // 32768

// Chunked scan config
#define NCHUNK  64
#define CLEN    (SEQ / NCHUNK)   // 32

// inproj tiling
#define RTILE   24
#define XPAD    60

// Workspace layout (floats). zb/xd/cb/yb/sbuf hold fp16 (2 halfs per float slot).
#define OFF_WF   ((size_t)0)
#define OFF_BF   ((size_t)18496)
#define OFF_WOC  ((size_t)18848)
#define OFF_G    ((size_t)19744)
#define OFF_P    ((size_t)21792)                    // 64*64 = 4096 floats
#define OFF_FLAG ((size_t)25888)                    // 32 words
#define OFF_DC   ((size_t)25920)                    // BL*4 floats
#define OFF_ZB   ((size_t)157000)                   // BL*128 halfs = BL*64 floats
#define OFF_XD   (OFF_ZB + (size_t)BL*64)           // BL*196 halfs = BL*98 floats
#define OFF_CB   (OFF_XD + (size_t)BL*98)           // BL*32 halfs  = BL*16 floats
#define OFF_YB   (OFF_CB + (size_t)BL*16)           // BL*128 halfs = BL*64 floats
#define OFF_SB   (OFF_YB + (size_t)BL*64)           // 64*64*1024 halfs
// total ≈ 10.2M floats ≈ 41 MB

// ---------------------------------------------------------------------------
// Kernel 1: Wf = W_lin@W_in ; bf = b_lin@W_in ; W_oc = W_out@W_cls.
// Also zeroes the G accumulator and the head-fold counter.
__global__ void fuse_w_kernel(const float* __restrict__ W_lin,
                              const float* __restrict__ b_lin,
                              const float* __restrict__ W_in,
                              const float* __restrict__ W_out,
                              const float* __restrict__ W_cls,
                              float* __restrict__ Wf, float* __restrict__ bf,
                              float* __restrict__ Woc, float* __restrict__ G,
                              unsigned* __restrict__ flags) {
    int idx = blockIdx.x * 256 + threadIdx.x;
    if (idx < BATCH * D_INNER) G[idx] = 0.f;
    if (idx < 8) flags[idx] = 0u;
    if (idx < 58 * D_IN_PROJ) {
        int r = idx / D_IN_PROJ;
        int j = idx - r * D_IN_PROJ;
        const float* v = (r < IN_DIM) ? (W_lin + r * D_MODEL) : b_lin;
        float acc = 0.f;
#pragma unroll 8
        for (int m = 0; m < D_MODEL; ++m) acc += v[m] * W_in[m * D_IN_PROJ + j];
        if (r < IN_DIM) Wf[r * D_IN_PROJ + j] = acc;
        else            bf[j] = acc;
    } else if (idx < 58 * D_IN_PROJ + D_INNER * OUT_DIM) {
        int idx2 = idx - 58 * D_IN_PROJ;
        int i = idx2 / OUT_DIM;
        int o = idx2 - i * OUT_DIM;
        float acc = 0.f;
#pragma unroll 8
        for (int j = 0; j < D_MODEL; ++j)
            acc += W_out[i * D_MODEL + j] * W_cls[j * OUT_DIM + o];
        Woc[i * OUT_DIM + o] = acc;
    }
}

// ---------------------------------------------------------------------------
// Kernel 2: LDS-staged in-projection. Block: 24 rows x 324 cols.
// Outputs quantized to fp16: z cols (0..127) -> zbh (stride 128 halfs),
// conv-in + dt cols -> xdh (stride 196 halfs).
__global__ __launch_bounds__(256) void inproj_kernel(
        const float* __restrict__ x,
        const float* __restrict__ Wf,
        const float* __restrict__ bf,
        __half* __restrict__ zbh,
        __half* __restrict__ xdh) {
    __shared__ float xs[RTILE][XPAD];
    int r0 = blockIdx.x * RTILE;
    for (int i = threadIdx.x; i < RTILE * IN_DIM; i += 256) {
        size_t g = (size_t)r0 * IN_DIM + i;
        float v = (g < (size_t)BL * IN_DIM) ? x[g] : 0.f;
        xs[i / IN_DIM][i % IN_DIM] = v;
    }
    __syncthreads();
    if (threadIdx.x >= 243) return;
    int rset = threadIdx.x / 81;
    int cg   = threadIdx.x - rset * 81;
    int j0   = cg * 4;
    float4 bias = *(const float4*)(bf + j0);
    float4 acc[8];
#pragma unroll
    for (int r = 0; r < 8; ++r) acc[r] = bias;
    const float* w = Wf + j0;
    const float* xrow = &xs[rset * 8][0];
#pragma unroll 2
    for (int kc = 0; kc < 14; ++kc) {
        int k = kc * 4;
        float4 wv0 = *(const float4*)(w + (size_t)(k + 0) * D_IN_PROJ);
        float4 wv1 = *(const float4*)(w + (size_t)(k + 1) * D_IN_PROJ);
        float4 wv2 = *(const float4*)(w + (size_t)(k + 2) * D_IN_PROJ);
        float4 wv3 = *(const float4*)(w + (size_t)(k + 3) * D_IN_PROJ);
#pragma unroll
        for (int r = 0; r < 8; ++r) {
            float4 xv = *(const float4*)(xrow + r * XPAD + k);
            acc[r].x += xv.x * wv0.x + xv.y * wv1.x + xv.z * wv2.x + xv.w * wv3.x;
            acc[r].y += xv.x * wv0.y + xv.y * wv1.y + xv.z * wv2.y + xv.w * wv3.y;
            acc[r].z += xv.x * wv0.z + xv.y * wv1.z + xv.z * wv2.z + xv.w * wv3.z;
            acc[r].w += xv.x * wv0.w + xv.y * wv1.w + xv.z * wv2.w + xv.w * wv3.w;
        }
    }
    {
        float4 wv = *(const float4*)(w + (size_t)56 * D_IN_PROJ);
#pragma unroll
        for (int r = 0; r < 8; ++r) {
            float xv = xrow[r * XPAD + 56];
            acc[r].x += xv * wv.x; acc[r].y += xv * wv.y;
            acc[r].z += xv * wv.z; acc[r].w += xv * wv.w;
        }
    }
#pragma unroll
    for (int r = 0; r < 8; ++r) {
        int row = r0 + rset * 8 + r;
        if (row < BL) {
            __half2 h01 = __floats2half2_rn(acc[r].x, acc[r].y);
            __half2 h23 = __floats2half2_rn(acc[r].z, acc[r].w);
            uint2 u;
            u.x = *(unsigned*)&h01;
            u.y = *(unsigned*)&h23;
            if (j0 < D_INNER)
                *(uint2*)(zbh + (size_t)row * D_INNER + j0) = u;
            else
                *(uint2*)(xdh + (size_t)row * D_XD + (j0 - D_INNER)) = u;
        }
    }
}

// ---------------------------------------------------------------------------
// Conv + dt prologue (fp16 xd input, fp32 compute).
__device__ __forceinline__ void conv_prologue(
        const __half* __restrict__ xdh,
        const float* __restrict__ conv_w, const float* __restrict__ conv_b,
        const float* __restrict__ dt_bias, const float* __restrict__ A_log,
        size_t rbase, int c, int tid,
        float (*xbt)[D_XBC], float (*ddl)[8]) {
    if (tid < D_XBC) {
        int ch = tid;
        float w0 = conv_w[ch*4+0], w1 = conv_w[ch*4+1];
        float w2 = conv_w[ch*4+2], w3 = conv_w[ch*4+3];
        float cb = conv_b[ch];
        const __half* src = xdh + rbase * D_XD + ch;
        float vm1 = 0.f, vm2 = 0.f, vm3 = 0.f;
        if (c > 0) {
            vm1 = __half2float(src[-(int)D_XD]);
            vm2 = __half2float(src[-2*(int)D_XD]);
            vm3 = __half2float(src[-3*(int)D_XD]);
        }
#pragma unroll
        for (int i = 0; i < CLEN; ++i) {
            float v0 = __half2float(src[(size_t)i * D_XD]);
            float a = cb + v0 * w3 + vm1 * w2 + vm2 * w1 + vm3 * w0;
            xbt[i][ch] = a / (1.f + expf(-a));   // SiLU
            vm3 = vm2; vm2 = vm1; vm1 = v0;
        }
    } else {
        int idx = tid - D_XBC;       // 0..63
        int h = idx >> 4;
        int i0 = idx & 15;
        float db = dt_bias[h];
        float nA = -expf(A_log[h]);
#pragma unroll
        for (int i = i0; i < CLEN; i += 16) {
            float v = __half2float(xdh[(rbase + i) * D_XD + 192 + h]) + db;
            float dtv = (v > 20.f) ? v : log1pf(expf(v));
            ddl[i][h * 2]     = dtv;
            ddl[i][h * 2 + 1] = expf(dtv * nA);
        }
    }
}

// ---------------------------------------------------------------------------
// Phase 1: conv once -> UNSEEDED scan with fused C-dot -> writes:
//   y_u (fp16, includes D*x), C rows (fp16), cumdec (fp32),
//   chunk-final state (fp16 sbuf), chunk decay product (Pbuf).
// Seeded outputs are reconstructed in phase3 as y = y_u + cumdec*(C·seed).
__global__ __launch_bounds__(256) void scan_phase1_kernel(
        const __half* __restrict__ xdh,
        const float* __restrict__ conv_w, const float* __restrict__ conv_b,
        const float* __restrict__ dt_bias, const float* __restrict__ A_log,
        const float* __restrict__ Dp,
        __half* __restrict__ sbuf, float* __restrict__ Pbuf,
        __half* __restrict__ ybuf, __half* __restrict__ Cbuf,
        float* __restrict__ Dcum) {
    int b = blockIdx.x >> 6;          // NCHUNK=64
    int c = blockIdx.x & (NCHUNK - 1);
    int tid = threadIdx.x;
    __shared__ float xbt[CLEN][D_XBC];     // 24 KB conv outputs
    __shared__ float ddl[CLEN][8];         // 1 KB {dt,dec}x4
    __shared__ __half yl[CLEN][D_INNER];   // 8 KB y_u staging
    __shared__ float dcl[CLEN * 4];        // 0.5 KB cumdec staging
    size_t rbase = (size_t)b * SEQ + (size_t)c * CLEN;
    conv_prologue(xdh, conv_w, conv_b, dt_bias, A_log, rbase, c, tid, xbt, ddl);
    __syncthreads();
    int h = tid >> 6, lane = tid & 63;
    int p = lane >> 1, n0 = (lane & 1) * 16;
    float Dh = Dp[h];
    float4 s0 = make_float4(0.f,0.f,0.f,0.f), s1 = s0, s2 = s0, s3 = s0;
    float pacc = 1.f;
#pragma unroll 4
    for (int i = 0; i < CLEN; ++i) {
        float dtv = ddl[i][h * 2];
        float dec = ddl[i][h * 2 + 1];
        float xv = xbt[i][h * HEADDIM + p];
        const float* Bp = &xbt[i][D_INNER + n0];
        const float* Cp = &xbt[i][D_INNER + D_STATE + n0];
        float4 B0 = *(const float4*)(Bp + 0);
        float4 B1 = *(const float4*)(Bp + 4);
        float4 B2 = *(const float4*)(Bp + 8);
        float4 B3 = *(const float4*)(Bp + 12);
        float4 C0 = *(const float4*)(Cp + 0);
        float4 C1 = *(const float4*)(Cp + 4);
        float4 C2 = *(const float4*)(Cp + 8);
        float4 C3 = *(const float4*)(Cp + 12);
        float coef = dtv * xv;
        s0.x = s0.x*dec + coef*B0.x; s0.y = s0.y*dec + coef*B0.y;
        s0.z = s0.z*dec + coef*B0.z; s0.w = s0.w*dec + coef*B0.w;
        s1.x = s1.x*dec + coef*B1.x; s1.y = s1.y*dec + coef*B1.y;
        s1.z = s1.z*dec + coef*B1.z; s1.w = s1.w*dec + coef*B1.w;
        s2.x = s2.x*dec + coef*B2.x; s2.y = s2.y*dec + coef*B2.y;
        s2.z = s2.z*dec + coef*B2.z; s2.w = s2.w*dec + coef*B2.w;
        s3.x = s3.x*dec + coef*B3.x; s3.y = s3.y*dec + coef*B3.y;
        s3.z = s3.z*dec + coef*B3.z; s3.w = s3.w*dec + coef*B3.w;
        pacc *= dec;
        float part = s0.x*C0.x + s0.y*C0.y + s0.z*C0.z + s0.w*C0.w
                   + s1.x*C1.x + s1.y*C1.y + s1.z*C1.z + s1.w*C1.w
                   + s2.x*C2.x + s2.y*C2.y + s2.z*C2.z + s2.w*C2.w
                   + s3.x*C3.x + s3.y*C3.y + s3.z*C3.z + s3.w*C3.w;
        part += __shfl_xor(part, 1);
        if (lane == 0) dcl[i * 4 + h] = pacc;
        if ((lane & 1) == 0)
            yl[i][h * HEADDIM + p] = __float2half(part + Dh * xv);
    }
    int bh = b * NHEADS + h;
    __half2 hs[8];
    hs[0] = __floats2half2_rn(s0.x, s0.y); hs[1] = __floats2half2_rn(s0.z, s0.w);
    hs[2] = __floats2half2_rn(s1.x, s1.y); hs[3] = __floats2half2_rn(s1.z, s1.w);
    hs[4] = __floats2half2_rn(s2.x, s2.y); hs[5] = __floats2half2_rn(s2.z, s2.w);
    hs[6] = __floats2half2_rn(s3.x, s3.y); hs[7] = __floats2half2_rn(s3.z, s3.w);
    uint4* sp = (uint4*)(sbuf + ((size_t)bh * NCHUNK + c) * 1024) + lane * 2;
    sp[0] = *(uint4*)&hs[0];
    sp[1] = *(uint4*)&hs[4];
    if (lane == 0) Pbuf[bh * NCHUNK + c] = pacc;
    __syncthreads();
    // y_u out: CLEN*128 halfs = 512 uint4, coalesced
    {
        const uint4* ysrc = (const uint4*)&yl[0][0];
        uint4* ydst = (uint4*)(ybuf + rbase * D_INNER);
        ydst[tid]       = ysrc[tid];
        ydst[tid + 256] = ysrc[tid + 256];
    }
    // C out: CLEN*32 halfs = 512 half2
    for (int idx = tid; idx < CLEN * 16; idx += 256) {
        int r  = idx >> 4;
        int n2 = (idx & 15) * 2;
        __half2 hv = __floats2half2_rn(xbt[r][D_INNER + D_STATE + n2],
                                       xbt[r][D_INNER + D_STATE + n2 + 1]);
        *((__half2*)(Cbuf + (rbase + r) * D_STATE + n2)) = hv;
    }
    // cumdec out: CLEN*4 floats
    if (tid < CLEN * 4) Dcum[rbase * 4 + tid] = dcl[tid];
}

// ---------------------------------------------------------------------------
// Phase 2 (parallel): LDS-staged chunk-state combine.
// Grid = 64 bh x 4 column-quarters = 256 blocks (1/CU). Each block stages all
// 64 chunk states for its 128 columns (32 KB LDS, coalesced), runs the serial
// chain in registers with explicit prefetch, stores the EXCLUSIVE prefix back.
__global__ __launch_bounds__(256) void scan_phase2_kernel(
        __half* __restrict__ sbuf, const float* __restrict__ Pbuf) {
    __shared__ unsigned sl[NCHUNK][128];   // 32 KB
    __shared__ float Pl[NCHUNK];
    int bh = blockIdx.x >> 2;
    int q  = blockIdx.x & 3;
    int tid = threadIdx.x;
    unsigned* s32 = (unsigned*)sbuf;
    size_t base = (size_t)bh * NCHUNK * 512 + (size_t)q * 128;
    if (tid < NCHUNK) Pl[tid] = Pbuf[bh * NCHUNK + tid];
    for (int k = tid; k < NCHUNK * 128; k += 256) {
        int c = k >> 7, j = k & 127;
        sl[c][j] = s32[base + (size_t)c * 512 + j];
    }
    __syncthreads();
    if (tid < 128) {
        float rx = 0.f, ry = 0.f;
        unsigned v = sl[0][tid];
#pragma unroll 8
        for (int c = 0; c < NCHUNK; ++c) {
            unsigned vn = (c + 1 < NCHUNK) ? sl[c + 1][tid] : 0u;
            float Pv = Pl[c];
            __half2 hv = *(__half2*)&v;
            float2 t = __half22float2(hv);
            __half2 hr = __floats2half2_rn(rx, ry);
            sl[c][tid] = *(unsigned*)&hr;
            rx = rx * Pv + t.x;
            ry = ry * Pv + t.y;
            v = vn;
        }
    }
    __syncthreads();
    for (int k = tid; k < NCHUNK * 128; k += 256) {
        int c = k >> 7, j = k & 127;
        s32[base + (size_t)c * 512 + j] = sl[c][j];
    }
}

// ---------------------------------------------------------------------------
// Phase 3 (lite): y = y_u + cumdec*(C·seed), then gate*silu(z) + RMSNorm + G.
// The LAST block to finish additionally computes the classifier head
// (removes one dependent kernel launch).
__global__ __launch_bounds__(256) void scan_phase3_kernel(
        const __half* __restrict__ ybuf, const __half* __restrict__ Cbuf,
        const float* __restrict__ Dcum, const __half* __restrict__ zbh,
        const __half* __restrict__ sbuf, const float* __restrict__ norm_w,
        float* __restrict__ G, unsigned* __restrict__ flags,
        const float* __restrict__ Woc, const float* __restrict__ b_cls,
        float* __restrict__ out) {
    int b = blockIdx.x >> 6;          // NCHUNK=64
    int c = blockIdx.x & (NCHUNK - 1);
    int tid = threadIdx.x;
    __shared__ float ylds[CLEN][D_INNER];   // 16 KB
    __shared__ float dcl[CLEN * 4];         // 0.5 KB
    __shared__ float red[4][D_INNER];       // 2 KB
    __shared__ unsigned amlast;
    size_t rbase = (size_t)b * SEQ + (size_t)c * CLEN;
    int h = tid >> 6, lane = tid & 63;
    int p = lane >> 1, n0 = (lane & 1) * 16;
    int bh = b * NHEADS + h;
    // seed load first (long-latency global, overlaps ybuf staging)
    const uint4* sp = (const uint4*)(sbuf + ((size_t)bh * NCHUNK + c) * 1024) + lane * 2;
    uint4 u0 = sp[0], u1 = sp[1];
    // stage y_u -> fp32 LDS (coalesced half2)
    {
        const __half2* ysrc = (const __half2*)(ybuf + rbase * D_INNER);
        for (int idx = tid; idx < CLEN * D_INNER / 2; idx += 256) {
            float2 f = __half22float2(ysrc[idx]);
            int r  = idx >> 6;
            int c2 = (idx & 63) * 2;
            ylds[r][c2]     = f.x;
            ylds[r][c2 + 1] = f.y;
        }
    }
    if (tid < CLEN * 4) dcl[tid] = Dcum[rbase * 4 + tid];
    // unpack fp16 seed -> fp32 regs (state dims n0..n0+15 for row p)
    float4 s0, s1, s2, s3;
    {
        const __half2* hp0 = (const __half2*)&u0;
        const __half2* hp1 = (const __half2*)&u1;
        float2 f;
        f = __half22float2(hp0[0]); s0.x = f.x; s0.y = f.y;
        f = __half22float2(hp0[1]); s0.z = f.x; s0.w = f.y;
        f = __half22float2(hp0[2]); s1.x = f.x; s1.y = f.y;
        f = __half22float2(hp0[3]); s1.z = f.x; s1.w = f.y;
        f = __half22float2(hp1[0]); s2.x = f.x; s2.y = f.y;
        f = __half22float2(hp1[1]); s2.z = f.x; s2.w = f.y;
        f = __half22float2(hp1[2]); s3.x = f.x; s3.y = f.y;
        f = __half22float2(hp1[3]); s3.z = f.x; s3.w = f.y;
    }
    __syncthreads();
#pragma unroll 4
    for (int i = 0; i < CLEN; ++i) {
        const uint4* cp = (const uint4*)(Cbuf + (rbase + i) * D_STATE + n0);
        uint4 ca = cp[0], cb = cp[1];
        const __half2* cha = (const __half2*)&ca;
        const __half2* chb = (const __half2*)&cb;
        float2 f0 = __half22float2(cha[0]);
        float2 f1 = __half22float2(cha[1]);
        float2 f2 = __half22float2(cha[2]);
        float2 f3 = __half22float2(cha[3]);
        float2 f4 = __half22float2(chb[0]);
        float2 f5 = __half22float2(chb[1]);
        float2 f6 = __half22float2(chb[2]);
        float2 f7 = __half22float2(chb[3]);
        float part = s0.x*f0.x + s0.y*f0.y + s0.z*f1.x + s0.w*f1.y
                   + s1.x*f2.x + s1.y*f2.y + s1.z*f3.x + s1.w*f3.y
                   + s2.x*f4.x + s2.y*f4.y + s2.z*f5.x + s2.w*f5.y
                   + s3.x*f6.x + s3.y*f6.y + s3.z*f7.x + s3.w*f7.y;
        part += __shfl_xor(part, 1);
        if ((lane & 1) == 0)
            ylds[i][h * HEADDIM + p] += dcl[i * 4 + h] * part;
    }
    __syncthreads();
    // gate + RMSNorm from LDS; wave h handles rows r = h, h+4, ...
    float acc0 = 0.f, acc1 = 0.f;
    for (int r = h; r < CLEN; r += 4) {
        size_t bl = rbase + r;
        float2 yv = *(const float2*)(&ylds[r][lane * 2]);
        float2 zv = __half22float2(*((const __half2*)(zbh + bl * D_INNER) + lane));
        float g0 = yv.x * (zv.x / (1.f + expf(-zv.x)));
        float g1 = yv.y * (zv.y / (1.f + expf(-zv.y)));
        float sq = g0 * g0 + g1 * g1;
#pragma unroll
        for (int m = 1; m < 64; m <<= 1) sq += __shfl_xor(sq, m);
        float rms = 1.0f / sqrtf(sq * (1.f / 128.f) + 1e-5f);
        acc0 += g0 * rms;
        acc1 += g1 * rms;
    }
    red[h][lane * 2]     = acc0;
    red[h][lane * 2 + 1] = acc1;
    __syncthreads();
    if (tid < D_INNER) {
        float sg = red[0][tid] + red[1][tid] + red[2][tid] + red[3][tid];
        atomicAdd(&G[b * D_INNER + tid], sg * norm_w[tid]);
    }
    // ---- last-block head fold ----
    __syncthreads();   // drains the G atomics (syncthreads waits all mem ops)
    if (tid == 0) {
        __threadfence();
        amlast = (atomicAdd(&flags[0], 1u) == (unsigned)(BATCH * NCHUNK - 1)) ? 1u : 0u;
    }
    __syncthreads();
    if (amlast) {
        __threadfence();
        if (tid < BATCH * OUT_DIM) {
            int bb = tid / OUT_DIM, o = tid - bb * OUT_DIM;
            float acc = 0.f;
#pragma unroll 8
            for (int i = 0; i < D_INNER; ++i) {
                float gv = __hip_atomic_load(&G[bb * D_INNER + i],
                                             __ATOMIC_RELAXED,
                                             __HIP_MEMORY_SCOPE_AGENT);
                acc += gv * Woc[i * OUT_DIM + o];
            }
            out[bb * OUT_DIM + o] = acc * (1.f / (float)SEQ) + b_cls[o];
        }
    }
}

// ---------------------------------------------------------------------------
extern "C" void kernel_launch(void* const* d_in, const int* in_sizes, int n_in,
                              void* d_out, int out_size, void* d_ws, size_t ws_size,
                              hipStream_t stream) {
    const float* x       = (const float*)d_in[0];
    const float* W_lin   = (const float*)d_in[1];
    const float* b_lin   = (const float*)d_in[2];
    const float* W_in    = (const float*)d_in[3];
    const float* conv_w  = (const float*)d_in[4];
    const float* conv_b  = (const float*)d_in[5];
    const float* dt_bias = (const float*)d_in[6];
    const float* A_log   = (const float*)d_in[7];
    const float* Dp      = (const float*)d_in[8];
    const float* norm_w  = (const float*)d_in[9];
    const float* W_out   = (const float*)d_in[10];
    const float* W_cls   = (const float*)d_in[11];
    const float* b_cls   = (const float*)d_in[12];
    float* out = (float*)d_out;

    float* ws = (float*)d_ws;
    float* Wf      = ws + OFF_WF;
    float* bf      = ws + OFF_BF;
    float* Woc     = ws + OFF_WOC;
    float* G       = ws + OFF_G;
    float* Pbuf    = ws + OFF_P;
    unsigned* flags = (unsigned*)(ws + OFF_FLAG);
    float* Dcum  = ws + OFF_DC;
    __half* zbh  = (__half*)(ws + OFF_ZB);
    __half* xdh  = (__half*)(ws + OFF_XD);
    __half* Cbh  = (__half*)(ws + OFF_CB);
    __half* ybh  = (__half*)(ws + OFF_YB);
    __half* sbuf = (__half*)(ws + OFF_SB);

    // 1) fused weight precompute (also zeroes G + head counter)
    fuse_w_kernel<<<(58 * D_IN_PROJ + D_INNER * OUT_DIM + 255) / 256, 256, 0, stream>>>(
        W_lin, b_lin, W_in, W_out, W_cls, Wf, bf, Woc, G, flags);

    // 2) in-projection (LDS-staged, 24 rows/block; fp16 z / xd outputs)
    inproj_kernel<<<(BL + RTILE - 1) / RTILE, 256, 0, stream>>>(x, Wf, bf, zbh, xdh);

    // 3) chunked selective scan: conv+recurrence once (phase1), parallel
    //    LDS-staged seed combine (phase2), correction+gating+head (phase3).
    scan_phase1_kernel<<<BATCH * NCHUNK, 256, 0, stream>>>(
        xdh, conv_w, conv_b, dt_bias, A_log, Dp, sbuf, Pbuf, ybh, Cbh, Dcum);
    scan_phase2_kernel<<<256, 256, 0, stream>>>(sbuf, Pbuf);
    scan_phase3_kernel<<<BATCH * NCHUNK, 256, 0, stream>>>(
        ybh, Cbh, Dcum, zbh, sbuf, norm_w, G, flags, Woc, b_cls, out);
}

// Round 4
// 170.419 us; speedup vs baseline: 1.8223x; 1.0944x over previous
//
#include <hip/hip_runtime.h>
#include <hip/hip_fp16.h>
#include <cmath>

// Problem constants
#define BATCH   16
#define SEQ     2048
#define IN_DIM  57
#define D_MODEL 64
#define HEADDIM 32
#define D_STATE 32
#define OUT_DIM 6
#define D_INNER 128
#define NHEADS  4
#define D_CONV  4
#define D_XBC   192          // D_INNER + 2*D_STATE
#define D_XD    196          // conv channels (192) + dt (4)
#define D_IN_PROJ 324        // 2*D_INNER + 2*D_STATE + NHEADS
#define BL      (BATCH*SEQ)  // 32768

// Chunked scan config
#define NCHUNK  64
#define CLEN    (SEQ / NCHUNK)   // 32
#define SUBL    16               // phase3 rows per block (half chunk)

// inproj tiling
#define RTILE   24
#define XPAD    60

// Workspace layout (floats). zb/xd/cb/yb/sbuf hold fp16 (2 halfs per float slot).
#define OFF_WF   ((size_t)0)
#define OFF_BF   ((size_t)18496)
#define OFF_WOC  ((size_t)18848)
#define OFF_G    ((size_t)19744)
#define OFF_P    ((size_t)21792)                    // 64*64 = 4096 floats
#define OFF_DC   ((size_t)25920)                    // BL*4 floats
#define OFF_ZB   ((size_t)157000)                   // BL*128 halfs = BL*64 floats
#define OFF_XD   (OFF_ZB + (size_t)BL*64)           // BL*196 halfs = BL*98 floats
#define OFF_CB   (OFF_XD + (size_t)BL*98)           // BL*32 halfs  = BL*16 floats
#define OFF_YB   (OFF_CB + (size_t)BL*16)           // BL*128 halfs = BL*64 floats
#define OFF_SB   (OFF_YB + (size_t)BL*64)           // 64*64*1024 halfs
// total ≈ 10.2M floats ≈ 41 MB

// ---------------------------------------------------------------------------
// Kernel 1: Wf = W_lin@W_in ; bf = b_lin@W_in ; W_oc = W_out@W_cls.
// Also zeroes the G accumulator.
__global__ void fuse_w_kernel(const float* __restrict__ W_lin,
                              const float* __restrict__ b_lin,
                              const float* __restrict__ W_in,
                              const float* __restrict__ W_out,
                              const float* __restrict__ W_cls,
                              float* __restrict__ Wf, float* __restrict__ bf,
                              float* __restrict__ Woc, float* __restrict__ G) {
    int idx = blockIdx.x * 256 + threadIdx.x;
    if (idx < BATCH * D_INNER) G[idx] = 0.f;
    if (idx < 58 * D_IN_PROJ) {
        int r = idx / D_IN_PROJ;
        int j = idx - r * D_IN_PROJ;
        const float* v = (r < IN_DIM) ? (W_lin + r * D_MODEL) : b_lin;
        float acc = 0.f;
#pragma unroll 8
        for (int m = 0; m < D_MODEL; ++m) acc += v[m] * W_in[m * D_IN_PROJ + j];
        if (r < IN_DIM) Wf[r * D_IN_PROJ + j] = acc;
        else            bf[j] = acc;
    } else if (idx < 58 * D_IN_PROJ + D_INNER * OUT_DIM) {
        int idx2 = idx - 58 * D_IN_PROJ;
        int i = idx2 / OUT_DIM;
        int o = idx2 - i * OUT_DIM;
        float acc = 0.f;
#pragma unroll 8
        for (int j = 0; j < D_MODEL; ++j)
            acc += W_out[i * D_MODEL + j] * W_cls[j * OUT_DIM + o];
        Woc[i * OUT_DIM + o] = acc;
    }
}

// ---------------------------------------------------------------------------
// Kernel 2: LDS-staged in-projection. Block: 24 rows x 324 cols.
// Outputs quantized to fp16: z cols (0..127) -> zbh (stride 128 halfs),
// conv-in + dt cols -> xdh (stride 196 halfs).
__global__ __launch_bounds__(256) void inproj_kernel(
        const float* __restrict__ x,
        const float* __restrict__ Wf,
        const float* __restrict__ bf,
        __half* __restrict__ zbh,
        __half* __restrict__ xdh) {
    __shared__ float xs[RTILE][XPAD];
    int r0 = blockIdx.x * RTILE;
    for (int i = threadIdx.x; i < RTILE * IN_DIM; i += 256) {
        size_t g = (size_t)r0 * IN_DIM + i;
        float v = (g < (size_t)BL * IN_DIM) ? x[g] : 0.f;
        xs[i / IN_DIM][i % IN_DIM] = v;
    }
    __syncthreads();
    if (threadIdx.x >= 243) return;
    int rset = threadIdx.x / 81;
    int cg   = threadIdx.x - rset * 81;
    int j0   = cg * 4;
    float4 bias = *(const float4*)(bf + j0);
    float4 acc[8];
#pragma unroll
    for (int r = 0; r < 8; ++r) acc[r] = bias;
    const float* w = Wf + j0;
    const float* xrow = &xs[rset * 8][0];
#pragma unroll 2
    for (int kc = 0; kc < 14; ++kc) {
        int k = kc * 4;
        float4 wv0 = *(const float4*)(w + (size_t)(k + 0) * D_IN_PROJ);
        float4 wv1 = *(const float4*)(w + (size_t)(k + 1) * D_IN_PROJ);
        float4 wv2 = *(const float4*)(w + (size_t)(k + 2) * D_IN_PROJ);
        float4 wv3 = *(const float4*)(w + (size_t)(k + 3) * D_IN_PROJ);
#pragma unroll
        for (int r = 0; r < 8; ++r) {
            float4 xv = *(const float4*)(xrow + r * XPAD + k);
            acc[r].x += xv.x * wv0.x + xv.y * wv1.x + xv.z * wv2.x + xv.w * wv3.x;
            acc[r].y += xv.x * wv0.y + xv.y * wv1.y + xv.z * wv2.y + xv.w * wv3.y;
            acc[r].z += xv.x * wv0.z + xv.y * wv1.z + xv.z * wv2.z + xv.w * wv3.z;
            acc[r].w += xv.x * wv0.w + xv.y * wv1.w + xv.z * wv2.w + xv.w * wv3.w;
        }
    }
    {
        float4 wv = *(const float4*)(w + (size_t)56 * D_IN_PROJ);
#pragma unroll
        for (int r = 0; r < 8; ++r) {
            float xv = xrow[r * XPAD + 56];
            acc[r].x += xv * wv.x; acc[r].y += xv * wv.y;
            acc[r].z += xv * wv.z; acc[r].w += xv * wv.w;
        }
    }
#pragma unroll
    for (int r = 0; r < 8; ++r) {
        int row = r0 + rset * 8 + r;
        if (row < BL) {
            __half2 h01 = __floats2half2_rn(acc[r].x, acc[r].y);
            __half2 h23 = __floats2half2_rn(acc[r].z, acc[r].w);
            uint2 u;
            u.x = *(unsigned*)&h01;
            u.y = *(unsigned*)&h23;
            if (j0 < D_INNER)
                *(uint2*)(zbh + (size_t)row * D_INNER + j0) = u;
            else
                *(uint2*)(xdh + (size_t)row * D_XD + (j0 - D_INNER)) = u;
        }
    }
}

// ---------------------------------------------------------------------------
// Conv + dt prologue (fp16 xd input, fp32 compute).
__device__ __forceinline__ void conv_prologue(
        const __half* __restrict__ xdh,
        const float* __restrict__ conv_w, const float* __restrict__ conv_b,
        const float* __restrict__ dt_bias, const float* __restrict__ A_log,
        size_t rbase, int c, int tid,
        float (*xbt)[D_XBC], float (*ddl)[8]) {
    if (tid < D_XBC) {
        int ch = tid;
        float w0 = conv_w[ch*4+0], w1 = conv_w[ch*4+1];
        float w2 = conv_w[ch*4+2], w3 = conv_w[ch*4+3];
        float cb = conv_b[ch];
        const __half* src = xdh + rbase * D_XD + ch;
        float vm1 = 0.f, vm2 = 0.f, vm3 = 0.f;
        if (c > 0) {
            vm1 = __half2float(src[-(int)D_XD]);
            vm2 = __half2float(src[-2*(int)D_XD]);
            vm3 = __half2float(src[-3*(int)D_XD]);
        }
#pragma unroll
        for (int i = 0; i < CLEN; ++i) {
            float v0 = __half2float(src[(size_t)i * D_XD]);
            float a = cb + v0 * w3 + vm1 * w2 + vm2 * w1 + vm3 * w0;
            xbt[i][ch] = a / (1.f + expf(-a));   // SiLU
            vm3 = vm2; vm2 = vm1; vm1 = v0;
        }
    } else {
        int idx = tid - D_XBC;       // 0..63
        int h = idx >> 4;
        int i0 = idx & 15;
        float db = dt_bias[h];
        float nA = -expf(A_log[h]);
#pragma unroll
        for (int i = i0; i < CLEN; i += 16) {
            float v = __half2float(xdh[(rbase + i) * D_XD + 192 + h]) + db;
            float dtv = (v > 20.f) ? v : log1pf(expf(v));
            ddl[i][h * 2]     = dtv;
            ddl[i][h * 2 + 1] = expf(dtv * nA);
        }
    }
}

// ---------------------------------------------------------------------------
// Phase 1: conv once -> UNSEEDED scan with fused C-dot -> writes:
//   y_u (fp16, includes D*x), C rows (fp16), cumdec (fp32),
//   chunk-final state (fp16 sbuf), chunk decay product (Pbuf).
// Seeded outputs are reconstructed in phase3 as y = y_u + cumdec*(C·seed).
__global__ __launch_bounds__(256) void scan_phase1_kernel(
        const __half* __restrict__ xdh,
        const float* __restrict__ conv_w, const float* __restrict__ conv_b,
        const float* __restrict__ dt_bias, const float* __restrict__ A_log,
        const float* __restrict__ Dp,
        __half* __restrict__ sbuf, float* __restrict__ Pbuf,
        __half* __restrict__ ybuf, __half* __restrict__ Cbuf,
        float* __restrict__ Dcum) {
    int b = blockIdx.x >> 6;          // NCHUNK=64
    int c = blockIdx.x & (NCHUNK - 1);
    int tid = threadIdx.x;
    __shared__ float xbt[CLEN][D_XBC];     // 24 KB conv outputs
    __shared__ float ddl[CLEN][8];         // 1 KB {dt,dec}x4
    __shared__ __half yl[CLEN][D_INNER];   // 8 KB y_u staging
    __shared__ float dcl[CLEN * 4];        // 0.5 KB cumdec staging
    size_t rbase = (size_t)b * SEQ + (size_t)c * CLEN;
    conv_prologue(xdh, conv_w, conv_b, dt_bias, A_log, rbase, c, tid, xbt, ddl);
    __syncthreads();
    int h = tid >> 6, lane = tid & 63;
    int p = lane >> 1, n0 = (lane & 1) * 16;
    float Dh = Dp[h];
    float4 s0 = make_float4(0.f,0.f,0.f,0.f), s1 = s0, s2 = s0, s3 = s0;
    float pacc = 1.f;
#pragma unroll 4
    for (int i = 0; i < CLEN; ++i) {
        float dtv = ddl[i][h * 2];
        float dec = ddl[i][h * 2 + 1];
        float xv = xbt[i][h * HEADDIM + p];
        const float* Bp = &xbt[i][D_INNER + n0];
        const float* Cp = &xbt[i][D_INNER + D_STATE + n0];
        float4 B0 = *(const float4*)(Bp + 0);
        float4 B1 = *(const float4*)(Bp + 4);
        float4 B2 = *(const float4*)(Bp + 8);
        float4 B3 = *(const float4*)(Bp + 12);
        float4 C0 = *(const float4*)(Cp + 0);
        float4 C1 = *(const float4*)(Cp + 4);
        float4 C2 = *(const float4*)(Cp + 8);
        float4 C3 = *(const float4*)(Cp + 12);
        float coef = dtv * xv;
        s0.x = s0.x*dec + coef*B0.x; s0.y = s0.y*dec + coef*B0.y;
        s0.z = s0.z*dec + coef*B0.z; s0.w = s0.w*dec + coef*B0.w;
        s1.x = s1.x*dec + coef*B1.x; s1.y = s1.y*dec + coef*B1.y;
        s1.z = s1.z*dec + coef*B1.z; s1.w = s1.w*dec + coef*B1.w;
        s2.x = s2.x*dec + coef*B2.x; s2.y = s2.y*dec + coef*B2.y;
        s2.z = s2.z*dec + coef*B2.z; s2.w = s2.w*dec + coef*B2.w;
        s3.x = s3.x*dec + coef*B3.x; s3.y = s3.y*dec + coef*B3.y;
        s3.z = s3.z*dec + coef*B3.z; s3.w = s3.w*dec + coef*B3.w;
        pacc *= dec;
        float part = s0.x*C0.x + s0.y*C0.y + s0.z*C0.z + s0.w*C0.w
                   + s1.x*C1.x + s1.y*C1.y + s1.z*C1.z + s1.w*C1.w
                   + s2.x*C2.x + s2.y*C2.y + s2.z*C2.z + s2.w*C2.w
                   + s3.x*C3.x + s3.y*C3.y + s3.z*C3.z + s3.w*C3.w;
        part += __shfl_xor(part, 1);
        if (lane == 0) dcl[i * 4 + h] = pacc;
        if ((lane & 1) == 0)
            yl[i][h * HEADDIM + p] = __float2half(part + Dh * xv);
    }
    int bh = b * NHEADS + h;
    __half2 hs[8];
    hs[0] = __floats2half2_rn(s0.x, s0.y); hs[1] = __floats2half2_rn(s0.z, s0.w);
    hs[2] = __floats2half2_rn(s1.x, s1.y); hs[3] = __floats2half2_rn(s1.z, s1.w);
    hs[4] = __floats2half2_rn(s2.x, s2.y); hs[5] = __floats2half2_rn(s2.z, s2.w);
    hs[6] = __floats2half2_rn(s3.x, s3.y); hs[7] = __floats2half2_rn(s3.z, s3.w);
    uint4* sp = (uint4*)(sbuf + ((size_t)bh * NCHUNK + c) * 1024) + lane * 2;
    sp[0] = *(uint4*)&hs[0];
    sp[1] = *(uint4*)&hs[4];
    if (lane == 0) Pbuf[bh * NCHUNK + c] = pacc;
    __syncthreads();
    // y_u out: CLEN*128 halfs = 512 uint4, coalesced
    {
        const uint4* ysrc = (const uint4*)&yl[0][0];
        uint4* ydst = (uint4*)(ybuf + rbase * D_INNER);
        ydst[tid]       = ysrc[tid];
        ydst[tid + 256] = ysrc[tid + 256];
    }
    // C out: CLEN*32 halfs = 512 half2
    for (int idx = tid; idx < CLEN * 16; idx += 256) {
        int r  = idx >> 4;
        int n2 = (idx & 15) * 2;
        __half2 hv = __floats2half2_rn(xbt[r][D_INNER + D_STATE + n2],
                                       xbt[r][D_INNER + D_STATE + n2 + 1]);
        *((__half2*)(Cbuf + (rbase + r) * D_STATE + n2)) = hv;
    }
    // cumdec out: CLEN*4 floats
    if (tid < CLEN * 4) Dcum[rbase * 4 + tid] = dcl[tid];
}

// ---------------------------------------------------------------------------
// Phase 2 (parallel): LDS-staged chunk-state combine.
// Grid = 64 bh x 4 column-quarters = 256 blocks (1/CU). Each block stages all
// 64 chunk states for its 128 columns (32 KB LDS, coalesced), runs the serial
// chain in registers with explicit prefetch, stores the EXCLUSIVE prefix back.
__global__ __launch_bounds__(256) void scan_phase2_kernel(
        __half* __restrict__ sbuf, const float* __restrict__ Pbuf) {
    __shared__ unsigned sl[NCHUNK][128];   // 32 KB
    __shared__ float Pl[NCHUNK];
    int bh = blockIdx.x >> 2;
    int q  = blockIdx.x & 3;
    int tid = threadIdx.x;
    unsigned* s32 = (unsigned*)sbuf;
    size_t base = (size_t)bh * NCHUNK * 512 + (size_t)q * 128;
    if (tid < NCHUNK) Pl[tid] = Pbuf[bh * NCHUNK + tid];
    for (int k = tid; k < NCHUNK * 128; k += 256) {
        int c = k >> 7, j = k & 127;
        sl[c][j] = s32[base + (size_t)c * 512 + j];
    }
    __syncthreads();
    if (tid < 128) {
        float rx = 0.f, ry = 0.f;
        unsigned v = sl[0][tid];
#pragma unroll 8
        for (int c = 0; c < NCHUNK; ++c) {
            unsigned vn = (c + 1 < NCHUNK) ? sl[c + 1][tid] : 0u;
            float Pv = Pl[c];
            __half2 hv = *(__half2*)&v;
            float2 t = __half22float2(hv);
            __half2 hr = __floats2half2_rn(rx, ry);
            sl[c][tid] = *(unsigned*)&hr;
            rx = rx * Pv + t.x;
            ry = ry * Pv + t.y;
            v = vn;
        }
    }
    __syncthreads();
    for (int k = tid; k < NCHUNK * 128; k += 256) {
        int c = k >> 7, j = k & 127;
        s32[base + (size_t)c * 512 + j] = sl[c][j];
    }
}

// ---------------------------------------------------------------------------
// Phase 3 (lite, half-chunk): y = y_u + cumdec*(C·seed), then gate*silu(z)
// + RMSNorm + G accumulation. 2048 blocks x 16 rows: the correction uses the
// chunk-START seed + per-row cumulative decay, so any row subset of a chunk
// is independently correctable -> double the blocks, half the LDS, 8/CU.
__global__ __launch_bounds__(256) void scan_phase3_kernel(
        const __half* __restrict__ ybuf, const __half* __restrict__ Cbuf,
        const float* __restrict__ Dcum, const __half* __restrict__ zbh,
        const __half* __restrict__ sbuf, const float* __restrict__ norm_w,
        float* __restrict__ G) {
    int b  = blockIdx.x >> 7;         // 128 subchunks per batch
    int sc = blockIdx.x & 127;        // subchunk index
    int c  = sc >> 1;                 // parent chunk (seed source)
    int tid = threadIdx.x;
    __shared__ float ylds[SUBL][D_INNER];   // 8 KB
    __shared__ float dcl[SUBL * 4];         // 256 B
    __shared__ float red[4][D_INNER];       // 2 KB
    size_t rbase = (size_t)b * SEQ + (size_t)sc * SUBL;
    int h = tid >> 6, lane = tid & 63;
    int p = lane >> 1, n0 = (lane & 1) * 16;
    int bh = b * NHEADS + h;
    // seed load first (long-latency global, overlaps ybuf staging)
    const uint4* sp = (const uint4*)(sbuf + ((size_t)bh * NCHUNK + c) * 1024) + lane * 2;
    uint4 u0 = sp[0], u1 = sp[1];
    // stage y_u -> fp32 LDS (coalesced half2): SUBL*64 = 1024 half2
    {
        const __half2* ysrc = (const __half2*)(ybuf + rbase * D_INNER);
#pragma unroll
        for (int k = 0; k < 4; ++k) {
            int idx = tid + k * 256;
            float2 f = __half22float2(ysrc[idx]);
            int r  = idx >> 6;
            int c2 = (idx & 63) * 2;
            ylds[r][c2]     = f.x;
            ylds[r][c2 + 1] = f.y;
        }
    }
    if (tid < SUBL * 4) dcl[tid] = Dcum[rbase * 4 + tid];
    // unpack fp16 seed -> fp32 regs (state dims n0..n0+15 for row p)
    float4 s0, s1, s2, s3;
    {
        const __half2* hp0 = (const __half2*)&u0;
        const __half2* hp1 = (const __half2*)&u1;
        float2 f;
        f = __half22float2(hp0[0]); s0.x = f.x; s0.y = f.y;
        f = __half22float2(hp0[1]); s0.z = f.x; s0.w = f.y;
        f = __half22float2(hp0[2]); s1.x = f.x; s1.y = f.y;
        f = __half22float2(hp0[3]); s1.z = f.x; s1.w = f.y;
        f = __half22float2(hp1[0]); s2.x = f.x; s2.y = f.y;
        f = __half22float2(hp1[1]); s2.z = f.x; s2.w = f.y;
        f = __half22float2(hp1[2]); s3.x = f.x; s3.y = f.y;
        f = __half22float2(hp1[3]); s3.z = f.x; s3.w = f.y;
    }
    __syncthreads();
#pragma unroll 4
    for (int i = 0; i < SUBL; ++i) {
        const uint4* cp = (const uint4*)(Cbuf + (rbase + i) * D_STATE + n0);
        uint4 ca = cp[0], cb = cp[1];
        const __half2* cha = (const __half2*)&ca;
        const __half2* chb = (const __half2*)&cb;
        float2 f0 = __half22float2(cha[0]);
        float2 f1 = __half22float2(cha[1]);
        float2 f2 = __half22float2(cha[2]);
        float2 f3 = __half22float2(cha[3]);
        float2 f4 = __half22float2(chb[0]);
        float2 f5 = __half22float2(chb[1]);
        float2 f6 = __half22float2(chb[2]);
        float2 f7 = __half22float2(chb[3]);
        float part = s0.x*f0.x + s0.y*f0.y + s0.z*f1.x + s0.w*f1.y
                   + s1.x*f2.x + s1.y*f2.y + s1.z*f3.x + s1.w*f3.y
                   + s2.x*f4.x + s2.y*f4.y + s2.z*f5.x + s2.w*f5.y
                   + s3.x*f6.x + s3.y*f6.y + s3.z*f7.x + s3.w*f7.y;
        part += __shfl_xor(part, 1);
        if ((lane & 1) == 0)
            ylds[i][h * HEADDIM + p] += dcl[i * 4 + h] * part;
    }
    __syncthreads();
    // gate + RMSNorm from LDS; wave h handles rows r = h, h+4, ... (4 each)
    float acc0 = 0.f, acc1 = 0.f;
    for (int r = h; r < SUBL; r += 4) {
        size_t bl = rbase + r;
        float2 yv = *(const float2*)(&ylds[r][lane * 2]);
        float2 zv = __half22float2(*((const __half2*)(zbh + bl * D_INNER) + lane));
        float g0 = yv.x * (zv.x / (1.f + expf(-zv.x)));
        float g1 = yv.y * (zv.y / (1.f + expf(-zv.y)));
        float sq = g0 * g0 + g1 * g1;
#pragma unroll
        for (int m = 1; m < 64; m <<= 1) sq += __shfl_xor(sq, m);
        float rms = 1.0f / sqrtf(sq * (1.f / 128.f) + 1e-5f);
        acc0 += g0 * rms;
        acc1 += g1 * rms;
    }
    red[h][lane * 2]     = acc0;
    red[h][lane * 2 + 1] = acc1;
    __syncthreads();
    if (tid < D_INNER) {
        float sg = red[0][tid] + red[1][tid] + red[2][tid] + red[3][tid];
        atomicAdd(&G[b * D_INNER + tid], sg * norm_w[tid]);
    }
}

// ---------------------------------------------------------------------------
// Kernel 6: out[b][o] = b_cls[o] + (G[b] @ W_oc)[o] / SEQ
__global__ void head_kernel(const float* __restrict__ G,
                            const float* __restrict__ Woc,
                            const float* __restrict__ b_cls,
                            float* __restrict__ out) {
    int tid = threadIdx.x;
    if (tid >= BATCH * OUT_DIM) return;
    int b = tid / OUT_DIM, o = tid - b * OUT_DIM;
    float acc = 0.f;
#pragma unroll 8
    for (int i = 0; i < D_INNER; ++i)
        acc += G[b * D_INNER + i] * Woc[i * OUT_DIM + o];
    out[b * OUT_DIM + o] = acc * (1.f / (float)SEQ) + b_cls[o];
}

// ---------------------------------------------------------------------------
extern "C" void kernel_launch(void* const* d_in, const int* in_sizes, int n_in,
                              void* d_out, int out_size, void* d_ws, size_t ws_size,
                              hipStream_t stream) {
    const float* x       = (const float*)d_in[0];
    const float* W_lin   = (const float*)d_in[1];
    const float* b_lin   = (const float*)d_in[2];
    const float* W_in    = (const float*)d_in[3];
    const float* conv_w  = (const float*)d_in[4];
    const float* conv_b  = (const float*)d_in[5];
    const float* dt_bias = (const float*)d_in[6];
    const float* A_log   = (const float*)d_in[7];
    const float* Dp      = (const float*)d_in[8];
    const float* norm_w  = (const float*)d_in[9];
    const float* W_out   = (const float*)d_in[10];
    const float* W_cls   = (const float*)d_in[11];
    const float* b_cls   = (const float*)d_in[12];
    float* out = (float*)d_out;

    float* ws = (float*)d_ws;
    float* Wf    = ws + OFF_WF;
    float* bf    = ws + OFF_BF;
    float* Woc   = ws + OFF_WOC;
    float* G     = ws + OFF_G;
    float* Pbuf  = ws + OFF_P;
    float* Dcum  = ws + OFF_DC;
    __half* zbh  = (__half*)(ws + OFF_ZB);
    __half* xdh  = (__half*)(ws + OFF_XD);
    __half* Cbh  = (__half*)(ws + OFF_CB);
    __half* ybh  = (__half*)(ws + OFF_YB);
    __half* sbuf = (__half*)(ws + OFF_SB);

    // 1) fused weight precompute (also zeroes G — no separate memset)
    fuse_w_kernel<<<(58 * D_IN_PROJ + D_INNER * OUT_DIM + 255) / 256, 256, 0, stream>>>(
        W_lin, b_lin, W_in, W_out, W_cls, Wf, bf, Woc, G);

    // 2) in-projection (LDS-staged, 24 rows/block; fp16 z / xd outputs)
    inproj_kernel<<<(BL + RTILE - 1) / RTILE, 256, 0, stream>>>(x, Wf, bf, zbh, xdh);

    // 3) chunked selective scan: conv+recurrence once (phase1), parallel
    //    LDS-staged seed combine (phase2), half-chunk correction+gating (phase3).
    scan_phase1_kernel<<<BATCH * NCHUNK, 256, 0, stream>>>(
        xdh, conv_w, conv_b, dt_bias, A_log, Dp, sbuf, Pbuf, ybh, Cbh, Dcum);
    scan_phase2_kernel<<<256, 256, 0, stream>>>(sbuf, Pbuf);
    scan_phase3_kernel<<<BATCH * 128, 256, 0, stream>>>(
        ybh, Cbh, Dcum, zbh, sbuf, norm_w, G);

    // 4) classifier head
    head_kernel<<<1, 128, 0, stream>>>(G, Woc, b_cls, out);
}

// Round 5
// 168.131 us; speedup vs baseline: 1.8471x; 1.0136x over previous
//
#include <hip/hip_runtime.h>
#include <hip/hip_fp16.h>
#include <cmath>

// Problem constants
#define BATCH   16
#define SEQ     2048
#define IN_DIM  57
#define D_MODEL 64
#define HEADDIM 32
#define D_STATE 32
#define OUT_DIM 6
#define D_INNER 128
#define NHEADS  4
#define D_CONV  4
#define D_XBC   192          // D_INNER + 2*D_STATE
#define D_IN_PROJ 324        // 2*D_INNER + 2*D_STATE + NHEADS
#define BL      (BATCH*SEQ)  // 32768

// Chunked scan config
#define NCHUNK  64
#define CLEN    (SEQ / NCHUNK)   // 32
#define SUBL    16               // phase3 rows per block (half chunk)
#define XDS     200              // xdl row stride (halfs)

// Workspace layout (floats). zb/cb/yb/sbuf hold fp16 (2 halfs per float slot).
#define OFF_WF   ((size_t)0)
#define OFF_BF   ((size_t)18496)
#define OFF_WOC  ((size_t)18848)
#define OFF_P    ((size_t)21792)                    // 64*64 = 4096 floats
#define OFF_DC   ((size_t)25920)                    // BL*4 floats
#define OFF_ZB   ((size_t)157000)                   // BL*128 halfs = BL*64 floats
#define OFF_CB   (OFF_ZB + (size_t)BL*64)           // BL*32 halfs  = BL*16 floats
#define OFF_YB   (OFF_CB + (size_t)BL*16)           // BL*128 halfs = BL*64 floats
#define OFF_SB   (OFF_YB + (size_t)BL*64)           // 64*64*1024 halfs

// ---------------------------------------------------------------------------
// Kernel 1: Wf = W_lin@W_in ; bf = b_lin@W_in ; W_oc = W_out@W_cls.
// Also initializes out = b_cls (phase3 accumulates the head into out).
__global__ void fuse_w_kernel(const float* __restrict__ W_lin,
                              const float* __restrict__ b_lin,
                              const float* __restrict__ W_in,
                              const float* __restrict__ W_out,
                              const float* __restrict__ W_cls,
                              float* __restrict__ Wf, float* __restrict__ bf,
                              float* __restrict__ Woc,
                              const float* __restrict__ b_cls,
                              float* __restrict__ out) {
    int idx = blockIdx.x * 256 + threadIdx.x;
    if (idx < BATCH * OUT_DIM) out[idx] = b_cls[idx % OUT_DIM];
    if (idx < 58 * D_IN_PROJ) {
        int r = idx / D_IN_PROJ;
        int j = idx - r * D_IN_PROJ;
        const float* v = (r < IN_DIM) ? (W_lin + r * D_MODEL) : b_lin;
        float acc = 0.f;
#pragma unroll 8
        for (int m = 0; m < D_MODEL; ++m) acc += v[m] * W_in[m * D_IN_PROJ + j];
        if (r < IN_DIM) Wf[r * D_IN_PROJ + j] = acc;
        else            bf[j] = acc;
    } else if (idx < 58 * D_IN_PROJ + D_INNER * OUT_DIM) {
        int idx2 = idx - 58 * D_IN_PROJ;
        int i = idx2 / OUT_DIM;
        int o = idx2 - i * OUT_DIM;
        float acc = 0.f;
#pragma unroll 8
        for (int j = 0; j < D_MODEL; ++j)
            acc += W_out[i * D_MODEL + j] * W_cls[j * OUT_DIM + o];
        Woc[i * OUT_DIM + o] = acc;
    }
}

// ---------------------------------------------------------------------------
// Mega kernel: per (batch, chunk) block does in-projection (incl. 3 halo
// rows), conv+SiLU, dt/softplus, and the unseeded scan — all from LDS.
// Eliminates the xdh HBM round trip and one kernel launch.
// LDS lifetime overlay keeps the block at ~39.2 KB -> 4 blocks/CU.
__global__ __launch_bounds__(256) void mega1_kernel(
        const float* __restrict__ x,
        const float* __restrict__ Wf, const float* __restrict__ bf,
        const float* __restrict__ conv_w, const float* __restrict__ conv_b,
        const float* __restrict__ dt_bias, const float* __restrict__ A_log,
        const float* __restrict__ Dp,
        __half* __restrict__ zbh,
        __half* __restrict__ sbuf, float* __restrict__ Pbuf,
        __half* __restrict__ ybuf, __half* __restrict__ Cbuf,
        float* __restrict__ Dcum) {
    __shared__ __align__(16) char smem[40112];
    float (*xs)[60]    = (float (*)[60])smem;              // 35x60 f32 (8.4 KB), dies after pass B
    float (*xbt)[D_XBC]= (float (*)[D_XBC])smem;           // 32x192 f32 (24.6 KB), overlays xs
    __half (*xdl)[XDS] = (__half (*)[XDS])(smem + 24576);  // 35x200 fp16 (14 KB), dies after conv
    __half (*yl)[D_INNER] = (__half (*)[D_INNER])(smem + 24576); // 32x128 fp16, overlays xdl
    float (*ddl)[8]    = (float (*)[8])(smem + 38576);     // 32x8 f32 (1 KB)
    float* dcl         = (float*)(smem + 39600);           // 128 f32 (0.5 KB)

    int b = blockIdx.x >> 6;          // NCHUNK=64
    int c = blockIdx.x & (NCHUNK - 1);
    int tid = threadIdx.x;
    long rbase = (long)b * SEQ + (long)c * CLEN;

    // ---- stage x rows rbase-3 .. rbase+31 (halo for conv) ----
    for (int i = tid; i < 35 * IN_DIM; i += 256) {
        int r = i / IN_DIM, k = i - r * IN_DIM;
        float v = 0.f;
        if (c > 0 || r >= 3) v = x[(rbase - 3 + r) * IN_DIM + k];
        xs[r][k] = v;
    }
    __syncthreads();

    // ---- pass A: xd columns (global j = 128..323) for all 35 rows ----
    if (tid < 245) {
        int rset = tid / 49, cg = tid - rset * 49;
        int j0 = 128 + cg * 4;
        float4 bias = *(const float4*)(bf + j0);
        float4 acc[7];
#pragma unroll
        for (int r = 0; r < 7; ++r) acc[r] = bias;
        const float* w = Wf + j0;
        const float* xrow = &xs[rset * 7][0];
#pragma unroll 2
        for (int kc = 0; kc < 14; ++kc) {
            int k = kc * 4;
            float4 wv0 = *(const float4*)(w + (size_t)(k + 0) * D_IN_PROJ);
            float4 wv1 = *(const float4*)(w + (size_t)(k + 1) * D_IN_PROJ);
            float4 wv2 = *(const float4*)(w + (size_t)(k + 2) * D_IN_PROJ);
            float4 wv3 = *(const float4*)(w + (size_t)(k + 3) * D_IN_PROJ);
#pragma unroll
            for (int r = 0; r < 7; ++r) {
                float4 xv = *(const float4*)(xrow + r * 60 + k);
                acc[r].x += xv.x * wv0.x + xv.y * wv1.x + xv.z * wv2.x + xv.w * wv3.x;
                acc[r].y += xv.x * wv0.y + xv.y * wv1.y + xv.z * wv2.y + xv.w * wv3.y;
                acc[r].z += xv.x * wv0.z + xv.y * wv1.z + xv.z * wv2.z + xv.w * wv3.z;
                acc[r].w += xv.x * wv0.w + xv.y * wv1.w + xv.z * wv2.w + xv.w * wv3.w;
            }
        }
        {
            float4 wv = *(const float4*)(w + (size_t)56 * D_IN_PROJ);
#pragma unroll
            for (int r = 0; r < 7; ++r) {
                float xv = xrow[r * 60 + 56];
                acc[r].x += xv * wv.x; acc[r].y += xv * wv.y;
                acc[r].z += xv * wv.z; acc[r].w += xv * wv.w;
            }
        }
#pragma unroll
        for (int r = 0; r < 7; ++r) {
            int row = rset * 7 + r;
            *(__half2*)&xdl[row][j0 - 128]     = __floats2half2_rn(acc[r].x, acc[r].y);
            *(__half2*)&xdl[row][j0 - 128 + 2] = __floats2half2_rn(acc[r].z, acc[r].w);
        }
    }

    // ---- pass B: z columns (j = 0..127) for rows 0..31, straight to HBM ----
    {
        int rset = tid >> 5, cg = tid & 31;
        int j0 = cg * 4;
        float4 bias = *(const float4*)(bf + j0);
        float4 acc[4];
#pragma unroll
        for (int r = 0; r < 4; ++r) acc[r] = bias;
        const float* w = Wf + j0;
        const float* xrow = &xs[3 + rset * 4][0];
#pragma unroll 2
        for (int kc = 0; kc < 14; ++kc) {
            int k = kc * 4;
            float4 wv0 = *(const float4*)(w + (size_t)(k + 0) * D_IN_PROJ);
            float4 wv1 = *(const float4*)(w + (size_t)(k + 1) * D_IN_PROJ);
            float4 wv2 = *(const float4*)(w + (size_t)(k + 2) * D_IN_PROJ);
            float4 wv3 = *(const float4*)(w + (size_t)(k + 3) * D_IN_PROJ);
#pragma unroll
            for (int r = 0; r < 4; ++r) {
                float4 xv = *(const float4*)(xrow + r * 60 + k);
                acc[r].x += xv.x * wv0.x + xv.y * wv1.x + xv.z * wv2.x + xv.w * wv3.x;
                acc[r].y += xv.x * wv0.y + xv.y * wv1.y + xv.z * wv2.y + xv.w * wv3.y;
                acc[r].z += xv.x * wv0.z + xv.y * wv1.z + xv.z * wv2.z + xv.w * wv3.z;
                acc[r].w += xv.x * wv0.w + xv.y * wv1.w + xv.z * wv2.w + xv.w * wv3.w;
            }
        }
        {
            float4 wv = *(const float4*)(w + (size_t)56 * D_IN_PROJ);
#pragma unroll
            for (int r = 0; r < 4; ++r) {
                float xv = xrow[r * 60 + 56];
                acc[r].x += xv * wv.x; acc[r].y += xv * wv.y;
                acc[r].z += xv * wv.z; acc[r].w += xv * wv.w;
            }
        }
#pragma unroll
        for (int r = 0; r < 4; ++r) {
            long row = rbase + rset * 4 + r;
            __half2 h01 = __floats2half2_rn(acc[r].x, acc[r].y);
            __half2 h23 = __floats2half2_rn(acc[r].z, acc[r].w);
            uint2 u;
            u.x = *(unsigned*)&h01;
            u.y = *(unsigned*)&h23;
            *(uint2*)(zbh + row * D_INNER + j0) = u;
        }
    }
    __syncthreads();   // xs dead; xbt may now overlay it

    // ---- conv + SiLU (threads 0..191) and dt softplus/decay (192..255) ----
    if (tid < D_XBC) {
        int ch = tid;
        float w0 = conv_w[ch*4+0], w1 = conv_w[ch*4+1];
        float w2 = conv_w[ch*4+2], w3 = conv_w[ch*4+3];
        float cb = conv_b[ch];
        float vm1 = 0.f, vm2 = 0.f, vm3 = 0.f;
        if (c > 0) {
            vm1 = __half2float(xdl[2][ch]);
            vm2 = __half2float(xdl[1][ch]);
            vm3 = __half2float(xdl[0][ch]);
        }
#pragma unroll
        for (int i = 0; i < CLEN; ++i) {
            float v0 = __half2float(xdl[i + 3][ch]);
            float a = cb + v0 * w3 + vm1 * w2 + vm2 * w1 + vm3 * w0;
            xbt[i][ch] = a / (1.f + expf(-a));   // SiLU
            vm3 = vm2; vm2 = vm1; vm1 = v0;
        }
    } else {
        int idx = tid - D_XBC;       // 0..63
        int h = idx >> 4;
        int i0 = idx & 15;
        float db = dt_bias[h];
        float nA = -expf(A_log[h]);
#pragma unroll
        for (int i = i0; i < CLEN; i += 16) {
            float v = __half2float(xdl[i + 3][192 + h]) + db;
            float dtv = (v > 20.f) ? v : log1pf(expf(v));
            ddl[i][h * 2]     = dtv;
            ddl[i][h * 2 + 1] = expf(dtv * nA);
        }
    }
    __syncthreads();   // xdl dead; yl may now overlay it

    // ---- unseeded scan with fused C-dot ----
    int h = tid >> 6, lane = tid & 63;
    int p = lane >> 1, n0 = (lane & 1) * 16;
    float Dh = Dp[h];
    float4 s0 = make_float4(0.f,0.f,0.f,0.f), s1 = s0, s2 = s0, s3 = s0;
    float pacc = 1.f;
#pragma unroll 4
    for (int i = 0; i < CLEN; ++i) {
        float dtv = ddl[i][h * 2];
        float dec = ddl[i][h * 2 + 1];
        float xv = xbt[i][h * HEADDIM + p];
        const float* Bp = &xbt[i][D_INNER + n0];
        const float* Cp = &xbt[i][D_INNER + D_STATE + n0];
        float4 B0 = *(const float4*)(Bp + 0);
        float4 B1 = *(const float4*)(Bp + 4);
        float4 B2 = *(const float4*)(Bp + 8);
        float4 B3 = *(const float4*)(Bp + 12);
        float4 C0 = *(const float4*)(Cp + 0);
        float4 C1 = *(const float4*)(Cp + 4);
        float4 C2 = *(const float4*)(Cp + 8);
        float4 C3 = *(const float4*)(Cp + 12);
        float coef = dtv * xv;
        s0.x = s0.x*dec + coef*B0.x; s0.y = s0.y*dec + coef*B0.y;
        s0.z = s0.z*dec + coef*B0.z; s0.w = s0.w*dec + coef*B0.w;
        s1.x = s1.x*dec + coef*B1.x; s1.y = s1.y*dec + coef*B1.y;
        s1.z = s1.z*dec + coef*B1.z; s1.w = s1.w*dec + coef*B1.w;
        s2.x = s2.x*dec + coef*B2.x; s2.y = s2.y*dec + coef*B2.y;
        s2.z = s2.z*dec + coef*B2.z; s2.w = s2.w*dec + coef*B2.w;
        s3.x = s3.x*dec + coef*B3.x; s3.y = s3.y*dec + coef*B3.y;
        s3.z = s3.z*dec + coef*B3.z; s3.w = s3.w*dec + coef*B3.w;
        pacc *= dec;
        float part = s0.x*C0.x + s0.y*C0.y + s0.z*C0.z + s0.w*C0.w
                   + s1.x*C1.x + s1.y*C1.y + s1.z*C1.z + s1.w*C1.w
                   + s2.x*C2.x + s2.y*C2.y + s2.z*C2.z + s2.w*C2.w
                   + s3.x*C3.x + s3.y*C3.y + s3.z*C3.z + s3.w*C3.w;
        part += __shfl_xor(part, 1);
        if (lane == 0) dcl[i * 4 + h] = pacc;
        if ((lane & 1) == 0)
            yl[i][h * HEADDIM + p] = __float2half(part + Dh * xv);
    }
    int bh = b * NHEADS + h;
    __half2 hs[8];
    hs[0] = __floats2half2_rn(s0.x, s0.y); hs[1] = __floats2half2_rn(s0.z, s0.w);
    hs[2] = __floats2half2_rn(s1.x, s1.y); hs[3] = __floats2half2_rn(s1.z, s1.w);
    hs[4] = __floats2half2_rn(s2.x, s2.y); hs[5] = __floats2half2_rn(s2.z, s2.w);
    hs[6] = __floats2half2_rn(s3.x, s3.y); hs[7] = __floats2half2_rn(s3.z, s3.w);
    uint4* sp = (uint4*)(sbuf + ((size_t)bh * NCHUNK + c) * 1024) + lane * 2;
    sp[0] = *(uint4*)&hs[0];
    sp[1] = *(uint4*)&hs[4];
    if (lane == 0) Pbuf[bh * NCHUNK + c] = pacc;
    __syncthreads();
    // y_u out: CLEN*128 halfs = 512 uint4, coalesced
    {
        const uint4* ysrc = (const uint4*)&yl[0][0];
        uint4* ydst = (uint4*)(ybuf + (size_t)rbase * D_INNER);
        ydst[tid]       = ysrc[tid];
        ydst[tid + 256] = ysrc[tid + 256];
    }
    // C out: CLEN*32 halfs = 512 half2
    for (int idx = tid; idx < CLEN * 16; idx += 256) {
        int r  = idx >> 4;
        int n2 = (idx & 15) * 2;
        __half2 hv = __floats2half2_rn(xbt[r][D_INNER + D_STATE + n2],
                                       xbt[r][D_INNER + D_STATE + n2 + 1]);
        *((__half2*)(Cbuf + ((size_t)rbase + r) * D_STATE + n2)) = hv;
    }
    // cumdec out: CLEN*4 floats
    if (tid < CLEN * 4) Dcum[(size_t)rbase * 4 + tid] = dcl[tid];
}

// ---------------------------------------------------------------------------
// Phase 2 (parallel): LDS-staged chunk-state combine.
// Grid = 64 bh x 4 column-quarters = 256 blocks (1/CU).
__global__ __launch_bounds__(256) void scan_phase2_kernel(
        __half* __restrict__ sbuf, const float* __restrict__ Pbuf) {
    __shared__ unsigned sl[NCHUNK][128];   // 32 KB
    __shared__ float Pl[NCHUNK];
    int bh = blockIdx.x >> 2;
    int q  = blockIdx.x & 3;
    int tid = threadIdx.x;
    unsigned* s32 = (unsigned*)sbuf;
    size_t base = (size_t)bh * NCHUNK * 512 + (size_t)q * 128;
    if (tid < NCHUNK) Pl[tid] = Pbuf[bh * NCHUNK + tid];
    for (int k = tid; k < NCHUNK * 128; k += 256) {
        int c = k >> 7, j = k & 127;
        sl[c][j] = s32[base + (size_t)c * 512 + j];
    }
    __syncthreads();
    if (tid < 128) {
        float rx = 0.f, ry = 0.f;
        unsigned v = sl[0][tid];
#pragma unroll 8
        for (int c = 0; c < NCHUNK; ++c) {
            unsigned vn = (c + 1 < NCHUNK) ? sl[c + 1][tid] : 0u;
            float Pv = Pl[c];
            __half2 hv = *(__half2*)&v;
            float2 t = __half22float2(hv);
            __half2 hr = __floats2half2_rn(rx, ry);
            sl[c][tid] = *(unsigned*)&hr;
            rx = rx * Pv + t.x;
            ry = ry * Pv + t.y;
            v = vn;
        }
    }
    __syncthreads();
    for (int k = tid; k < NCHUNK * 128; k += 256) {
        int c = k >> 7, j = k & 127;
        s32[base + (size_t)c * 512 + j] = sl[c][j];
    }
}

// ---------------------------------------------------------------------------
// Phase 3 (half-chunk): y = y_u + cumdec*(C·seed), gate*silu(z), RMSNorm,
// then each block adds its head contribution straight into out (plain
// device-scope atomics — no fence, no counter). 2048 blocks x 16 rows.
__global__ __launch_bounds__(256) void scan_phase3_kernel(
        const __half* __restrict__ ybuf, const __half* __restrict__ Cbuf,
        const float* __restrict__ Dcum, const __half* __restrict__ zbh,
        const __half* __restrict__ sbuf, const float* __restrict__ norm_w,
        const float* __restrict__ Woc, float* __restrict__ out) {
    int b  = blockIdx.x >> 7;         // 128 subchunks per batch
    int sc = blockIdx.x & 127;        // subchunk index
    int c  = sc >> 1;                 // parent chunk (seed source)
    int tid = threadIdx.x;
    __shared__ float ylds[SUBL][D_INNER];   // 8 KB
    __shared__ float dcl[SUBL * 4];         // 256 B
    __shared__ float red[4][D_INNER];       // 2 KB
    __shared__ float snw[D_INNER];          // 512 B
    size_t rbase = (size_t)b * SEQ + (size_t)sc * SUBL;
    int h = tid >> 6, lane = tid & 63;
    int p = lane >> 1, n0 = (lane & 1) * 16;
    int bh = b * NHEADS + h;
    const uint4* sp = (const uint4*)(sbuf + ((size_t)bh * NCHUNK + c) * 1024) + lane * 2;
    uint4 u0 = sp[0], u1 = sp[1];
    {
        const __half2* ysrc = (const __half2*)(ybuf + rbase * D_INNER);
#pragma unroll
        for (int k = 0; k < 4; ++k) {
            int idx = tid + k * 256;
            float2 f = __half22float2(ysrc[idx]);
            int r  = idx >> 6;
            int c2 = (idx & 63) * 2;
            ylds[r][c2]     = f.x;
            ylds[r][c2 + 1] = f.y;
        }
    }
    if (tid < SUBL * 4) dcl[tid] = Dcum[rbase * 4 + tid];
    float4 s0, s1, s2, s3;
    {
        const __half2* hp0 = (const __half2*)&u0;
        const __half2* hp1 = (const __half2*)&u1;
        float2 f;
        f = __half22float2(hp0[0]); s0.x = f.x; s0.y = f.y;
        f = __half22float2(hp0[1]); s0.z = f.x; s0.w = f.y;
        f = __half22float2(hp0[2]); s1.x = f.x; s1.y = f.y;
        f = __half22float2(hp0[3]); s1.z = f.x; s1.w = f.y;
        f = __half22float2(hp1[0]); s2.x = f.x; s2.y = f.y;
        f = __half22float2(hp1[1]); s2.z = f.x; s2.w = f.y;
        f = __half22float2(hp1[2]); s3.x = f.x; s3.y = f.y;
        f = __half22float2(hp1[3]); s3.z = f.x; s3.w = f.y;
    }
    __syncthreads();
#pragma unroll 4
    for (int i = 0; i < SUBL; ++i) {
        const uint4* cp = (const uint4*)(Cbuf + (rbase + i) * D_STATE + n0);
        uint4 ca = cp[0], cb = cp[1];
        const __half2* cha = (const __half2*)&ca;
        const __half2* chb = (const __half2*)&cb;
        float2 f0 = __half22float2(cha[0]);
        float2 f1 = __half22float2(cha[1]);
        float2 f2 = __half22float2(cha[2]);
        float2 f3 = __half22float2(cha[3]);
        float2 f4 = __half22float2(chb[0]);
        float2 f5 = __half22float2(chb[1]);
        float2 f6 = __half22float2(chb[2]);
        float2 f7 = __half22float2(chb[3]);
        float part = s0.x*f0.x + s0.y*f0.y + s0.z*f1.x + s0.w*f1.y
                   + s1.x*f2.x + s1.y*f2.y + s1.z*f3.x + s1.w*f3.y
                   + s2.x*f4.x + s2.y*f4.y + s2.z*f5.x + s2.w*f5.y
                   + s3.x*f6.x + s3.y*f6.y + s3.z*f7.x + s3.w*f7.y;
        part += __shfl_xor(part, 1);
        if ((lane & 1) == 0)
            ylds[i][h * HEADDIM + p] += dcl[i * 4 + h] * part;
    }
    __syncthreads();
    float acc0 = 0.f, acc1 = 0.f;
    for (int r = h; r < SUBL; r += 4) {
        size_t bl = rbase + r;
        float2 yv = *(const float2*)(&ylds[r][lane * 2]);
        float2 zv = __half22float2(*((const __half2*)(zbh + bl * D_INNER) + lane));
        float g0 = yv.x * (zv.x / (1.f + expf(-zv.x)));
        float g1 = yv.y * (zv.y / (1.f + expf(-zv.y)));
        float sq = g0 * g0 + g1 * g1;
#pragma unroll
        for (int m = 1; m < 64; m <<= 1) sq += __shfl_xor(sq, m);
        float rms = 1.0f / sqrtf(sq * (1.f / 128.f) + 1e-5f);
        acc0 += g0 * rms;
        acc1 += g1 * rms;
    }
    red[h][lane * 2]     = acc0;
    red[h][lane * 2 + 1] = acc1;
    __syncthreads();
    if (tid < D_INNER)
        snw[tid] = (red[0][tid] + red[1][tid] + red[2][tid] + red[3][tid])
                   * norm_w[tid];
    __syncthreads();
    if (tid < OUT_DIM) {
        float acc = 0.f;
#pragma unroll 8
        for (int i = 0; i < D_INNER; ++i)
            acc += snw[i] * Woc[i * OUT_DIM + tid];
        atomicAdd(&out[b * OUT_DIM + tid], acc * (1.f / (float)SEQ));
    }
}

// ---------------------------------------------------------------------------
extern "C" void kernel_launch(void* const* d_in, const int* in_sizes, int n_in,
                              void* d_out, int out_size, void* d_ws, size_t ws_size,
                              hipStream_t stream) {
    const float* x       = (const float*)d_in[0];
    const float* W_lin   = (const float*)d_in[1];
    const float* b_lin   = (const float*)d_in[2];
    const float* W_in    = (const float*)d_in[3];
    const float* conv_w  = (const float*)d_in[4];
    const float* conv_b  = (const float*)d_in[5];
    const float* dt_bias = (const float*)d_in[6];
    const float* A_log   = (const float*)d_in[7];
    const float* Dp      = (const float*)d_in[8];
    const float* norm_w  = (const float*)d_in[9];
    const float* W_out   = (const float*)d_in[10];
    const float* W_cls   = (const float*)d_in[11];
    const float* b_cls   = (const float*)d_in[12];
    float* out = (float*)d_out;

    float* ws = (float*)d_ws;
    float* Wf    = ws + OFF_WF;
    float* bf    = ws + OFF_BF;
    float* Woc   = ws + OFF_WOC;
    float* Pbuf  = ws + OFF_P;
    float* Dcum  = ws + OFF_DC;
    __half* zbh  = (__half*)(ws + OFF_ZB);
    __half* Cbh  = (__half*)(ws + OFF_CB);
    __half* ybh  = (__half*)(ws + OFF_YB);
    __half* sbuf = (__half*)(ws + OFF_SB);

    // 1) fused weight precompute (also initializes out = b_cls)
    fuse_w_kernel<<<(58 * D_IN_PROJ + D_INNER * OUT_DIM + 255) / 256, 256, 0, stream>>>(
        W_lin, b_lin, W_in, W_out, W_cls, Wf, bf, Woc, b_cls, out);

    // 2) mega kernel: in-projection + conv + dt + unseeded scan per chunk
    mega1_kernel<<<BATCH * NCHUNK, 256, 0, stream>>>(
        x, Wf, bf, conv_w, conv_b, dt_bias, A_log, Dp,
        zbh, sbuf, Pbuf, ybh, Cbh, Dcum);

    // 3) parallel LDS-staged chunk-state combine
    scan_phase2_kernel<<<256, 256, 0, stream>>>(sbuf, Pbuf);

    // 4) half-chunk correction + gating + RMSNorm + head accumulation
    scan_phase3_kernel<<<BATCH * 128, 256, 0, stream>>>(
        ybh, Cbh, Dcum, zbh, sbuf, norm_w, Woc, out);
}

// Round 6
// 150.387 us; speedup vs baseline: 2.0650x; 1.1180x over previous
//
#include <hip/hip_runtime.h>
#include <hip/hip_fp16.h>
#include <cmath>

// Problem constants
#define BATCH   16
#define SEQ     2048
#define IN_DIM  57
#define D_MODEL 64
#define HEADDIM 32
#define D_STATE 32
#define OUT_DIM 6
#define D_INNER 128
#define NHEADS  4
#define D_CONV  4
#define D_XBC   192          // D_INNER + 2*D_STATE
#define D_IN_PROJ 324        // 2*D_INNER + 2*D_STATE + NHEADS
#define BL      (BATCH*SEQ)  // 32768

// Chunked scan config
#define NCHUNK  64
#define CLEN    (SEQ / NCHUNK)   // 32
#define SUBL    16               // phase3 rows per block (half chunk)
#define XDS     200              // xdl row stride (halfs)

// MFMA inproj geometry: M=48 (3x16, rows 0..34 valid), K=64 (57 valid),
// N=336 (21x16, cols 0..323 valid).
#define NT      21               // n-tiles
#define WP_HALFS (NT * 2 * 64 * 8)   // 21504 halfs (packed B fragments)

typedef _Float16 f16x8 __attribute__((ext_vector_type(8)));
typedef float    f32x4 __attribute__((ext_vector_type(4)));

// Workspace layout (floats). zb/cb/yb/sbuf/wp hold fp16 (2 halfs per float slot).
#define OFF_WP   ((size_t)0)                        // 10752 floats (fp16 packed W)
#define OFF_BF   ((size_t)10752)                    // 324 -> pad 336
#define OFF_WOC  ((size_t)11088)                    // 768
#define OFF_P    ((size_t)11856)                    // 4096
#define OFF_DC   ((size_t)15952)                    // BL*4 = 131072
#define OFF_ZB   ((size_t)147024)                   // BL*128 halfs = BL*64 floats
#define OFF_CB   (OFF_ZB + (size_t)BL*64)           // BL*32 halfs  = BL*16 floats
#define OFF_YB   (OFF_CB + (size_t)BL*16)           // BL*128 halfs = BL*64 floats
#define OFF_SB   (OFF_YB + (size_t)BL*64)           // 64*64*1024 halfs

// ---------------------------------------------------------------------------
// Kernel 1: packed fp16 Wp = (W_lin@W_in) in MFMA B-fragment layout;
// bf = b_lin@W_in ; W_oc = W_out@W_cls ; out = b_cls.
// Pack: value (k,n) -> Wp[((t*2+kb)*64 + lane)*8 + j],
//   t=n>>4, kb=k>>5, lane=((k&31)>>3)*16 + (n&15), j=k&7.
__global__ void fuse_w_kernel(const float* __restrict__ W_lin,
                              const float* __restrict__ b_lin,
                              const float* __restrict__ W_in,
                              const float* __restrict__ W_out,
                              const float* __restrict__ W_cls,
                              __half* __restrict__ Wph, float* __restrict__ bf,
                              float* __restrict__ Woc,
                              const float* __restrict__ b_cls,
                              float* __restrict__ out) {
    int idx = blockIdx.x * 256 + threadIdx.x;
    if (idx < 64 * 336) {
        int k = idx / 336;
        int n = idx - k * 336;
        float acc = 0.f;
        if (k < IN_DIM && n < D_IN_PROJ) {
#pragma unroll 8
            for (int m = 0; m < D_MODEL; ++m)
                acc += W_lin[k * D_MODEL + m] * W_in[m * D_IN_PROJ + n];
        }
        int t = n >> 4, nl = n & 15;
        int kb = k >> 5, kr = k & 31;
        size_t pidx = (((size_t)(t * 2 + kb) * 64) + (kr >> 3) * 16 + nl) * 8 + (kr & 7);
        Wph[pidx] = __float2half(acc);
    } else if (idx < 64 * 336 + D_IN_PROJ) {
        int n = idx - 64 * 336;
        float acc = 0.f;
#pragma unroll 8
        for (int m = 0; m < D_MODEL; ++m)
            acc += b_lin[m] * W_in[m * D_IN_PROJ + n];
        bf[n] = acc;
    } else if (idx < 64 * 336 + D_IN_PROJ + D_INNER * OUT_DIM) {
        int idx2 = idx - (64 * 336 + D_IN_PROJ);
        int i = idx2 / OUT_DIM;
        int o = idx2 - i * OUT_DIM;
        float acc = 0.f;
#pragma unroll 8
        for (int j = 0; j < D_MODEL; ++j)
            acc += W_out[i * D_MODEL + j] * W_cls[j * OUT_DIM + o];
        Woc[i * OUT_DIM + o] = acc;
    } else if (idx < 64 * 336 + D_IN_PROJ + D_INNER * OUT_DIM + BATCH * OUT_DIM) {
        int idx3 = idx - (64 * 336 + D_IN_PROJ + D_INNER * OUT_DIM);
        out[idx3] = b_cls[idx3 % OUT_DIM];
    }
}

// ---------------------------------------------------------------------------
// Mega kernel: per (batch, chunk) block does the in-projection via fp16 MFMA
// (incl. 3 halo rows), conv+SiLU, dt/softplus, and the unseeded scan — all
// from LDS. LDS lifetime overlay keeps the block at ~39.2 KB -> 4 blocks/CU.
__global__ __launch_bounds__(256) void mega1_kernel(
        const float* __restrict__ x,
        const __half* __restrict__ Wph, const float* __restrict__ bf,
        const float* __restrict__ conv_w, const float* __restrict__ conv_b,
        const float* __restrict__ dt_bias, const float* __restrict__ A_log,
        const float* __restrict__ Dp,
        __half* __restrict__ zbh,
        __half* __restrict__ sbuf, float* __restrict__ Pbuf,
        __half* __restrict__ ybuf, __half* __restrict__ Cbuf,
        float* __restrict__ Dcum) {
    __shared__ __align__(16) char smem[40112];
    __half* xsh        = (__half*)smem;                    // 48x64 fp16 (6 KB), dies after MFMA
    __half (*zl)[128]  = (__half (*)[128])(smem + 6144);   // 32x128 fp16 (8 KB), dies after copy
    float (*xbt)[D_XBC]= (float (*)[D_XBC])smem;           // 32x192 f32 (24.6 KB), overlays xsh+zl
    __half (*xdl)[XDS] = (__half (*)[XDS])(smem + 24576);  // 35x200 fp16 (14 KB), dies after conv
    __half (*yl)[D_INNER] = (__half (*)[D_INNER])(smem + 24576); // 32x128 fp16, overlays xdl
    float (*ddl)[8]    = (float (*)[8])(smem + 38576);     // 32x8 f32 (1 KB)
    float* dcl         = (float*)(smem + 39600);           // 128 f32 (0.5 KB)

    int b = blockIdx.x >> 6;          // NCHUNK=64
    int c = blockIdx.x & (NCHUNK - 1);
    int tid = threadIdx.x;
    long rbase = (long)b * SEQ + (long)c * CLEN;

    // ---- stage x rows rbase-3 .. rbase+31 as fp16, XOR-swizzled ----
    for (int i = tid; i < 48 * 64; i += 256) {
        int r = i >> 6, k = i & 63;
        float v = 0.f;
        if (r < 35 && k < IN_DIM && (c > 0 || r >= 3))
            v = x[(rbase - 3 + r) * IN_DIM + k];
        xsh[i ^ ((r & 7) << 3)] = __float2half(v);
    }
    __syncthreads();

    // ---- MFMA in-projection: y[48][336] = x[48][64] @ Wf[64][336] + bf ----
    {
        int wid = tid >> 6, lane = tid & 63;
        int mrow = lane & 15, kg = lane >> 4;
        union { uint4 u; f16x8 f; } a[3][2];
#pragma unroll
        for (int mt = 0; mt < 3; ++mt)
#pragma unroll
            for (int kb = 0; kb < 2; ++kb) {
                int row = mt * 16 + mrow;
                int hidx = (row * 64 + kb * 32 + kg * 8) ^ ((row & 7) << 3);
                a[mt][kb].u = *(const uint4*)&xsh[hidx];
            }
        const uint4* wp4 = (const uint4*)Wph;
        for (int t = wid; t < NT; t += 4) {
            union { uint4 u; f16x8 f; } b0, b1;
            b0.u = wp4[(t * 2 + 0) * 64 + lane];
            b1.u = wp4[(t * 2 + 1) * 64 + lane];
            float bias = bf[t * 16 + mrow];
            f32x4 acc0 = {0.f, 0.f, 0.f, 0.f}, acc1 = acc0, acc2 = acc0;
            acc0 = __builtin_amdgcn_mfma_f32_16x16x32_f16(a[0][0].f, b0.f, acc0, 0, 0, 0);
            acc0 = __builtin_amdgcn_mfma_f32_16x16x32_f16(a[0][1].f, b1.f, acc0, 0, 0, 0);
            acc1 = __builtin_amdgcn_mfma_f32_16x16x32_f16(a[1][0].f, b0.f, acc1, 0, 0, 0);
            acc1 = __builtin_amdgcn_mfma_f32_16x16x32_f16(a[1][1].f, b1.f, acc1, 0, 0, 0);
            acc2 = __builtin_amdgcn_mfma_f32_16x16x32_f16(a[2][0].f, b0.f, acc2, 0, 0, 0);
            acc2 = __builtin_amdgcn_mfma_f32_16x16x32_f16(a[2][1].f, b1.f, acc2, 0, 0, 0);
            int n = t * 16 + mrow;
#pragma unroll
            for (int mt = 0; mt < 3; ++mt) {
                f32x4 av = (mt == 0) ? acc0 : (mt == 1) ? acc1 : acc2;
#pragma unroll
                for (int reg = 0; reg < 4; ++reg) {
                    int m = mt * 16 + kg * 4 + reg;   // C/D: row=(lane>>4)*4+reg [m89]
                    float v = av[reg] + bias;
                    if (t < 8) {
                        int zr = m - 3;
                        if (zr >= 0 && zr < 32) zl[zr][n] = __float2half(v);
                    } else {
                        int xc = n - 128;
                        if (m < 35 && xc < 196) xdl[m][xc] = __float2half(v);
                    }
                }
            }
        }
    }
    __syncthreads();

    // ---- flush z tile (contiguous 8 KB, coalesced) ----
    {
        const uint4* zsrc = (const uint4*)&zl[0][0];
        uint4* zdst = (uint4*)(zbh + (size_t)rbase * D_INNER);
        zdst[tid]       = zsrc[tid];
        zdst[tid + 256] = zsrc[tid + 256];
    }
    __syncthreads();   // zl reads done; xbt may overlay xsh+zl

    // ---- conv + SiLU (threads 0..191) and dt softplus/decay (192..255) ----
    if (tid < D_XBC) {
        int ch = tid;
        float w0 = conv_w[ch*4+0], w1 = conv_w[ch*4+1];
        float w2 = conv_w[ch*4+2], w3 = conv_w[ch*4+3];
        float cb = conv_b[ch];
        float vm1 = 0.f, vm2 = 0.f, vm3 = 0.f;
        if (c > 0) {
            vm1 = __half2float(xdl[2][ch]);
            vm2 = __half2float(xdl[1][ch]);
            vm3 = __half2float(xdl[0][ch]);
        }
#pragma unroll
        for (int i = 0; i < CLEN; ++i) {
            float v0 = __half2float(xdl[i + 3][ch]);
            float a = cb + v0 * w3 + vm1 * w2 + vm2 * w1 + vm3 * w0;
            xbt[i][ch] = a / (1.f + expf(-a));   // SiLU
            vm3 = vm2; vm2 = vm1; vm1 = v0;
        }
    } else {
        int idx = tid - D_XBC;       // 0..63
        int h = idx >> 4;
        int i0 = idx & 15;
        float db = dt_bias[h];
        float nA = -expf(A_log[h]);
#pragma unroll
        for (int i = i0; i < CLEN; i += 16) {
            float v = __half2float(xdl[i + 3][192 + h]) + db;
            float dtv = (v > 20.f) ? v : log1pf(expf(v));
            ddl[i][h * 2]     = dtv;
            ddl[i][h * 2 + 1] = expf(dtv * nA);
        }
    }
    __syncthreads();   // xdl dead; yl may now overlay it

    // ---- unseeded scan with fused C-dot ----
    int h = tid >> 6, lane = tid & 63;
    int p = lane >> 1, n0 = (lane & 1) * 16;
    float Dh = Dp[h];
    float4 s0 = make_float4(0.f,0.f,0.f,0.f), s1 = s0, s2 = s0, s3 = s0;
    float pacc = 1.f;
#pragma unroll 4
    for (int i = 0; i < CLEN; ++i) {
        float dtv = ddl[i][h * 2];
        float dec = ddl[i][h * 2 + 1];
        float xv = xbt[i][h * HEADDIM + p];
        const float* Bp = &xbt[i][D_INNER + n0];
        const float* Cp = &xbt[i][D_INNER + D_STATE + n0];
        float4 B0 = *(const float4*)(Bp + 0);
        float4 B1 = *(const float4*)(Bp + 4);
        float4 B2 = *(const float4*)(Bp + 8);
        float4 B3 = *(const float4*)(Bp + 12);
        float4 C0 = *(const float4*)(Cp + 0);
        float4 C1 = *(const float4*)(Cp + 4);
        float4 C2 = *(const float4*)(Cp + 8);
        float4 C3 = *(const float4*)(Cp + 12);
        float coef = dtv * xv;
        s0.x = s0.x*dec + coef*B0.x; s0.y = s0.y*dec + coef*B0.y;
        s0.z = s0.z*dec + coef*B0.z; s0.w = s0.w*dec + coef*B0.w;
        s1.x = s1.x*dec + coef*B1.x; s1.y = s1.y*dec + coef*B1.y;
        s1.z = s1.z*dec + coef*B1.z; s1.w = s1.w*dec + coef*B1.w;
        s2.x = s2.x*dec + coef*B2.x; s2.y = s2.y*dec + coef*B2.y;
        s2.z = s2.z*dec + coef*B2.z; s2.w = s2.w*dec + coef*B2.w;
        s3.x = s3.x*dec + coef*B3.x; s3.y = s3.y*dec + coef*B3.y;
        s3.z = s3.z*dec + coef*B3.z; s3.w = s3.w*dec + coef*B3.w;
        pacc *= dec;
        float part = s0.x*C0.x + s0.y*C0.y + s0.z*C0.z + s0.w*C0.w
                   + s1.x*C1.x + s1.y*C1.y + s1.z*C1.z + s1.w*C1.w
                   + s2.x*C2.x + s2.y*C2.y + s2.z*C2.z + s2.w*C2.w
                   + s3.x*C3.x + s3.y*C3.y + s3.z*C3.z + s3.w*C3.w;
        part += __shfl_xor(part, 1);
        if (lane == 0) dcl[i * 4 + h] = pacc;
        if ((lane & 1) == 0)
            yl[i][h * HEADDIM + p] = __float2half(part + Dh * xv);
    }
    int bh = b * NHEADS + h;
    __half2 hs[8];
    hs[0] = __floats2half2_rn(s0.x, s0.y); hs[1] = __floats2half2_rn(s0.z, s0.w);
    hs[2] = __floats2half2_rn(s1.x, s1.y); hs[3] = __floats2half2_rn(s1.z, s1.w);
    hs[4] = __floats2half2_rn(s2.x, s2.y); hs[5] = __floats2half2_rn(s2.z, s2.w);
    hs[6] = __floats2half2_rn(s3.x, s3.y); hs[7] = __floats2half2_rn(s3.z, s3.w);
    uint4* sp = (uint4*)(sbuf + ((size_t)bh * NCHUNK + c) * 1024) + lane * 2;
    sp[0] = *(uint4*)&hs[0];
    sp[1] = *(uint4*)&hs[4];
    if (lane == 0) Pbuf[bh * NCHUNK + c] = pacc;
    __syncthreads();
    // y_u out: CLEN*128 halfs = 512 uint4, coalesced
    {
        const uint4* ysrc = (const uint4*)&yl[0][0];
        uint4* ydst = (uint4*)(ybuf + (size_t)rbase * D_INNER);
        ydst[tid]       = ysrc[tid];
        ydst[tid + 256] = ysrc[tid + 256];
    }
    // C out: CLEN*32 halfs = 512 half2
    for (int idx = tid; idx < CLEN * 16; idx += 256) {
        int r  = idx >> 4;
        int n2 = (idx & 15) * 2;
        __half2 hv = __floats2half2_rn(xbt[r][D_INNER + D_STATE + n2],
                                       xbt[r][D_INNER + D_STATE + n2 + 1]);
        *((__half2*)(Cbuf + ((size_t)rbase + r) * D_STATE + n2)) = hv;
    }
    // cumdec out: CLEN*4 floats
    if (tid < CLEN * 4) Dcum[(size_t)rbase * 4 + tid] = dcl[tid];
}

// ---------------------------------------------------------------------------
// Phase 2 (parallel): LDS-staged chunk-state combine.
// Grid = 64 bh x 4 column-quarters = 256 blocks (1/CU).
__global__ __launch_bounds__(256) void scan_phase2_kernel(
        __half* __restrict__ sbuf, const float* __restrict__ Pbuf) {
    __shared__ unsigned sl[NCHUNK][128];   // 32 KB
    __shared__ float Pl[NCHUNK];
    int bh = blockIdx.x >> 2;
    int q  = blockIdx.x & 3;
    int tid = threadIdx.x;
    unsigned* s32 = (unsigned*)sbuf;
    size_t base = (size_t)bh * NCHUNK * 512 + (size_t)q * 128;
    if (tid < NCHUNK) Pl[tid] = Pbuf[bh * NCHUNK + tid];
    for (int k = tid; k < NCHUNK * 128; k += 256) {
        int c = k >> 7, j = k & 127;
        sl[c][j] = s32[base + (size_t)c * 512 + j];
    }
    __syncthreads();
    if (tid < 128) {
        float rx = 0.f, ry = 0.f;
        unsigned v = sl[0][tid];
#pragma unroll 8
        for (int c = 0; c < NCHUNK; ++c) {
            unsigned vn = (c + 1 < NCHUNK) ? sl[c + 1][tid] : 0u;
            float Pv = Pl[c];
            __half2 hv = *(__half2*)&v;
            float2 t = __half22float2(hv);
            __half2 hr = __floats2half2_rn(rx, ry);
            sl[c][tid] = *(unsigned*)&hr;
            rx = rx * Pv + t.x;
            ry = ry * Pv + t.y;
            v = vn;
        }
    }
    __syncthreads();
    for (int k = tid; k < NCHUNK * 128; k += 256) {
        int c = k >> 7, j = k & 127;
        s32[base + (size_t)c * 512 + j] = sl[c][j];
    }
}

// ---------------------------------------------------------------------------
// Phase 3 (half-chunk): y = y_u + cumdec*(C·seed), gate*silu(z), RMSNorm,
// then each block adds its head contribution straight into out (plain
// device-scope atomics — no fence, no counter). 2048 blocks x 16 rows.
__global__ __launch_bounds__(256) void scan_phase3_kernel(
        const __half* __restrict__ ybuf, const __half* __restrict__ Cbuf,
        const float* __restrict__ Dcum, const __half* __restrict__ zbh,
        const __half* __restrict__ sbuf, const float* __restrict__ norm_w,
        const float* __restrict__ Woc, float* __restrict__ out) {
    int b  = blockIdx.x >> 7;         // 128 subchunks per batch
    int sc = blockIdx.x & 127;        // subchunk index
    int c  = sc >> 1;                 // parent chunk (seed source)
    int tid = threadIdx.x;
    __shared__ float ylds[SUBL][D_INNER];   // 8 KB
    __shared__ float dcl[SUBL * 4];         // 256 B
    __shared__ float red[4][D_INNER];       // 2 KB
    __shared__ float snw[D_INNER];          // 512 B
    size_t rbase = (size_t)b * SEQ + (size_t)sc * SUBL;
    int h = tid >> 6, lane = tid & 63;
    int p = lane >> 1, n0 = (lane & 1) * 16;
    int bh = b * NHEADS + h;
    const uint4* sp = (const uint4*)(sbuf + ((size_t)bh * NCHUNK + c) * 1024) + lane * 2;
    uint4 u0 = sp[0], u1 = sp[1];
    {
        const __half2* ysrc = (const __half2*)(ybuf + rbase * D_INNER);
#pragma unroll
        for (int k = 0; k < 4; ++k) {
            int idx = tid + k * 256;
            float2 f = __half22float2(ysrc[idx]);
            int r  = idx >> 6;
            int c2 = (idx & 63) * 2;
            ylds[r][c2]     = f.x;
            ylds[r][c2 + 1] = f.y;
        }
    }
    if (tid < SUBL * 4) dcl[tid] = Dcum[rbase * 4 + tid];
    float4 s0, s1, s2, s3;
    {
        const __half2* hp0 = (const __half2*)&u0;
        const __half2* hp1 = (const __half2*)&u1;
        float2 f;
        f = __half22float2(hp0[0]); s0.x = f.x; s0.y = f.y;
        f = __half22float2(hp0[1]); s0.z = f.x; s0.w = f.y;
        f = __half22float2(hp0[2]); s1.x = f.x; s1.y = f.y;
        f = __half22float2(hp0[3]); s1.z = f.x; s1.w = f.y;
        f = __half22float2(hp1[0]); s2.x = f.x; s2.y = f.y;
        f = __half22float2(hp1[1]); s2.z = f.x; s2.w = f.y;
        f = __half22float2(hp1[2]); s3.x = f.x; s3.y = f.y;
        f = __half22float2(hp1[3]); s3.z = f.x; s3.w = f.y;
    }
    __syncthreads();
#pragma unroll 4
    for (int i = 0; i < SUBL; ++i) {
        const uint4* cp = (const uint4*)(Cbuf + (rbase + i) * D_STATE + n0);
        uint4 ca = cp[0], cb = cp[1];
        const __half2* cha = (const __half2*)&ca;
        const __half2* chb = (const __half2*)&cb;
        float2 f0 = __half22float2(cha[0]);
        float2 f1 = __half22float2(cha[1]);
        float2 f2 = __half22float2(cha[2]);
        float2 f3 = __half22float2(cha[3]);
        float2 f4 = __half22float2(chb[0]);
        float2 f5 = __half22float2(chb[1]);
        float2 f6 = __half22float2(chb[2]);
        float2 f7 = __half22float2(chb[3]);
        float part = s0.x*f0.x + s0.y*f0.y + s0.z*f1.x + s0.w*f1.y
                   + s1.x*f2.x + s1.y*f2.y + s1.z*f3.x + s1.w*f3.y
                   + s2.x*f4.x + s2.y*f4.y + s2.z*f5.x + s2.w*f5.y
                   + s3.x*f6.x + s3.y*f6.y + s3.z*f7.x + s3.w*f7.y;
        part += __shfl_xor(part, 1);
        if ((lane & 1) == 0)
            ylds[i][h * HEADDIM + p] += dcl[i * 4 + h] * part;
    }
    __syncthreads();
    float acc0 = 0.f, acc1 = 0.f;
    for (int r = h; r < SUBL; r += 4) {
        size_t bl = rbase + r;
        float2 yv = *(const float2*)(&ylds[r][lane * 2]);
        float2 zv = __half22float2(*((const __half2*)(zbh + bl * D_INNER) + lane));
        float g0 = yv.x * (zv.x / (1.f + expf(-zv.x)));
        float g1 = yv.y * (zv.y / (1.f + expf(-zv.y)));
        float sq = g0 * g0 + g1 * g1;
#pragma unroll
        for (int m = 1; m < 64; m <<= 1) sq += __shfl_xor(sq, m);
        float rms = 1.0f / sqrtf(sq * (1.f / 128.f) + 1e-5f);
        acc0 += g0 * rms;
        acc1 += g1 * rms;
    }
    red[h][lane * 2]     = acc0;
    red[h][lane * 2 + 1] = acc1;
    __syncthreads();
    if (tid < D_INNER)
        snw[tid] = (red[0][tid] + red[1][tid] + red[2][tid] + red[3][tid])
                   * norm_w[tid];
    __syncthreads();
    if (tid < OUT_DIM) {
        float acc = 0.f;
#pragma unroll 8
        for (int i = 0; i < D_INNER; ++i)
            acc += snw[i] * Woc[i * OUT_DIM + tid];
        atomicAdd(&out[b * OUT_DIM + tid], acc * (1.f / (float)SEQ));
    }
}

// ---------------------------------------------------------------------------
extern "C" void kernel_launch(void* const* d_in, const int* in_sizes, int n_in,
                              void* d_out, int out_size, void* d_ws, size_t ws_size,
                              hipStream_t stream) {
    const float* x       = (const float*)d_in[0];
    const float* W_lin   = (const float*)d_in[1];
    const float* b_lin   = (const float*)d_in[2];
    const float* W_in    = (const float*)d_in[3];
    const float* conv_w  = (const float*)d_in[4];
    const float* conv_b  = (const float*)d_in[5];
    const float* dt_bias = (const float*)d_in[6];
    const float* A_log   = (const float*)d_in[7];
    const float* Dp      = (const float*)d_in[8];
    const float* norm_w  = (const float*)d_in[9];
    const float* W_out   = (const float*)d_in[10];
    const float* W_cls   = (const float*)d_in[11];
    const float* b_cls   = (const float*)d_in[12];
    float* out = (float*)d_out;

    float* ws = (float*)d_ws;
    __half* Wph  = (__half*)(ws + OFF_WP);
    float* bf    = ws + OFF_BF;
    float* Woc   = ws + OFF_WOC;
    float* Pbuf  = ws + OFF_P;
    float* Dcum  = ws + OFF_DC;
    __half* zbh  = (__half*)(ws + OFF_ZB);
    __half* Cbh  = (__half*)(ws + OFF_CB);
    __half* ybh  = (__half*)(ws + OFF_YB);
    __half* sbuf = (__half*)(ws + OFF_SB);

    // 1) fused weight precompute: packed fp16 MFMA fragments + bias + head
    int nfw = 64 * 336 + D_IN_PROJ + D_INNER * OUT_DIM + BATCH * OUT_DIM;
    fuse_w_kernel<<<(nfw + 255) / 256, 256, 0, stream>>>(
        W_lin, b_lin, W_in, W_out, W_cls, Wph, bf, Woc, b_cls, out);

    // 2) mega kernel: MFMA in-projection + conv + dt + unseeded scan per chunk
    mega1_kernel<<<BATCH * NCHUNK, 256, 0, stream>>>(
        x, Wph, bf, conv_w, conv_b, dt_bias, A_log, Dp,
        zbh, sbuf, Pbuf, ybh, Cbh, Dcum);

    // 3) parallel LDS-staged chunk-state combine
    scan_phase2_kernel<<<256, 256, 0, stream>>>(sbuf, Pbuf);

    // 4) half-chunk correction + gating + RMSNorm + head accumulation
    scan_phase3_kernel<<<BATCH * 128, 256, 0, stream>>>(
        ybh, Cbh, Dcum, zbh, sbuf, norm_w, Woc, out);
}

// Round 7
// 144.107 us; speedup vs baseline: 2.1550x; 1.0436x over previous
//
#include <hip/hip_runtime.h>
#include <hip/hip_fp16.h>
#include <cmath>

// Problem constants
#define BATCH   16
#define SEQ     2048
#define IN_DIM  57
#define D_MODEL 64
#define HEADDIM 32
#define D_STATE 32
#define OUT_DIM 6
#define D_INNER 128
#define NHEADS  4
#define D_CONV  4
#define D_XBC   192          // D_INNER + 2*D_STATE
#define D_IN_PROJ 324        // 2*D_INNER + 2*D_STATE + NHEADS
#define BL      (BATCH*SEQ)  // 32768

// Chunked scan config
#define NCHUNK  64
#define CLEN    (SEQ / NCHUNK)   // 32
#define SUBL    16               // phase3 rows per block (half chunk)
#define XDS     200              // xdl row stride (halfs)

// MFMA inproj geometry: M=48 (3x16, rows 0..34 valid), K=64 (57 valid),
// N=336 (21x16, cols 0..323 valid).
#define NT      21               // n-tiles

typedef _Float16 f16x8 __attribute__((ext_vector_type(8)));
typedef float    f32x4 __attribute__((ext_vector_type(4)));

// mega1 LDS map (bytes). Lifetime phases:
//  [inproj]  xsh 0..6144, zl 6144..14336, xdl 14336..28336
//  [conv]    Xt 0..8192, B16 8192..10240, Bt 10240..12288, C16 12288..14336
//            (xsh/zl dead), xdl still live, dtl 30720..
//  [ssd]     Ml 14336..22528 (xdl dead), Ypack 22528..30720, then S reuses Ml
#define OXT   0
#define OB16  8192
#define OBT   10240
#define OC16  12288
#define OXDL  14336
#define OML   14336
#define OSL   14336
#define OYP   22528
#define ODTL  30720
#define OLSL  31232
#define OWL2  31744
#define ODCL  32000
#define SMEM_SZ 32512

// Workspace layout (floats). zb/cb/yb/sbuf/wp hold fp16.
#define OFF_WP   ((size_t)0)                        // 10752 floats (fp16 packed W)
#define OFF_BF   ((size_t)10752)                    // 324 -> pad 336
#define OFF_WOC  ((size_t)11088)                    // 768
#define OFF_P    ((size_t)11856)                    // 4096
#define OFF_DC   ((size_t)15952)                    // BL*4 = 131072
#define OFF_ZB   ((size_t)147024)                   // BL*128 halfs
#define OFF_CB   (OFF_ZB + (size_t)BL*64)           // BL*32 halfs
#define OFF_YB   (OFF_CB + (size_t)BL*16)           // BL*128 halfs (packed frag order)
#define OFF_SB   (OFF_YB + (size_t)BL*64)           // 64*64*1024 halfs

// Swizzled half-address within a [rows][32]-half fp16 buffer (64 B rows,
// 16B-block XOR by row&3 -> aligned b128 reads, <=4-way bank conflicts).
__device__ __forceinline__ int swz(int row, int j) {
    return row * 64 + (((j >> 3) ^ (row & 3)) << 4) + ((j & 7) << 1);
}
__device__ __forceinline__ int swz4(int row, int kg) {   // uint4 read addr
    return row * 64 + ((kg ^ (row & 3)) << 4);
}

// ---------------------------------------------------------------------------
// Kernel 1: packed fp16 Wp = (W_lin@W_in) in MFMA B-fragment layout;
// bf = b_lin@W_in ; W_oc = W_out@W_cls ; out = b_cls.
__global__ void fuse_w_kernel(const float* __restrict__ W_lin,
                              const float* __restrict__ b_lin,
                              const float* __restrict__ W_in,
                              const float* __restrict__ W_out,
                              const float* __restrict__ W_cls,
                              __half* __restrict__ Wph, float* __restrict__ bf,
                              float* __restrict__ Woc,
                              const float* __restrict__ b_cls,
                              float* __restrict__ out) {
    int idx = blockIdx.x * 256 + threadIdx.x;
    if (idx < 64 * 336) {
        int k = idx / 336;
        int n = idx - k * 336;
        float acc = 0.f;
        if (k < IN_DIM && n < D_IN_PROJ) {
#pragma unroll 8
            for (int m = 0; m < D_MODEL; ++m)
                acc += W_lin[k * D_MODEL + m] * W_in[m * D_IN_PROJ + n];
        }
        int t = n >> 4, nl = n & 15;
        int kb = k >> 5, kr = k & 31;
        size_t pidx = (((size_t)(t * 2 + kb) * 64) + (kr >> 3) * 16 + nl) * 8 + (kr & 7);
        Wph[pidx] = __float2half(acc);
    } else if (idx < 64 * 336 + D_IN_PROJ) {
        int n = idx - 64 * 336;
        float acc = 0.f;
#pragma unroll 8
        for (int m = 0; m < D_MODEL; ++m)
            acc += b_lin[m] * W_in[m * D_IN_PROJ + n];
        bf[n] = acc;
    } else if (idx < 64 * 336 + D_IN_PROJ + D_INNER * OUT_DIM) {
        int idx2 = idx - (64 * 336 + D_IN_PROJ);
        int i = idx2 / OUT_DIM;
        int o = idx2 - i * OUT_DIM;
        float acc = 0.f;
#pragma unroll 8
        for (int j = 0; j < D_MODEL; ++j)
            acc += W_out[i * D_MODEL + j] * W_cls[j * OUT_DIM + o];
        Woc[i * OUT_DIM + o] = acc;
    } else if (idx < 64 * 336 + D_IN_PROJ + D_INNER * OUT_DIM + BATCH * OUT_DIM) {
        int idx3 = idx - (64 * 336 + D_IN_PROJ + D_INNER * OUT_DIM);
        out[idx3] = b_cls[idx3 % OUT_DIM];
    }
}

// ---------------------------------------------------------------------------
// Mega kernel: MFMA in-projection -> conv/SiLU/dt -> SSD chunked scan on
// MFMA (G = C.B^T, M = mask(G), Y = M.X, S = (w.X)^T-weighted . B).
// 32.5 KB LDS -> 5 blocks/CU.
__global__ __launch_bounds__(256) void mega1_kernel(
        const float* __restrict__ x,
        const __half* __restrict__ Wph, const float* __restrict__ bf,
        const float* __restrict__ conv_w, const float* __restrict__ conv_b,
        const float* __restrict__ dt_bias, const float* __restrict__ A_log,
        const float* __restrict__ Dp,
        __half* __restrict__ zbh,
        __half* __restrict__ sbuf, float* __restrict__ Pbuf,
        __half* __restrict__ ybuf, __half* __restrict__ Cbuf,
        float* __restrict__ Dcum) {
    __shared__ __align__(16) char smem[SMEM_SZ];
    __half* xsh        = (__half*)smem;                    // 48x64 fp16 [inproj]
    __half (*zl)[128]  = (__half (*)[128])(smem + 6144);   // 32x128 fp16 [inproj]
    __half (*xdl)[XDS] = (__half (*)[XDS])(smem + OXDL);   // 35x200 fp16

    int b = blockIdx.x >> 6;          // NCHUNK=64
    int c = blockIdx.x & (NCHUNK - 1);
    int tid = threadIdx.x;
    long rbase = (long)b * SEQ + (long)c * CLEN;

    // ---- stage x rows rbase-3 .. rbase+31 as fp16, XOR-swizzled ----
    for (int i = tid; i < 48 * 64; i += 256) {
        int r = i >> 6, k = i & 63;
        float v = 0.f;
        if (r < 35 && k < IN_DIM && (c > 0 || r >= 3))
            v = x[(rbase - 3 + r) * IN_DIM + k];
        xsh[i ^ ((r & 7) << 3)] = __float2half(v);
    }
    __syncthreads();

    // ---- MFMA in-projection: y[48][336] = x[48][64] @ Wf[64][336] + bf ----
    {
        int wid = tid >> 6, lane = tid & 63;
        int mrow = lane & 15, kg = lane >> 4;
        union { uint4 u; f16x8 f; } a[3][2];
#pragma unroll
        for (int mt = 0; mt < 3; ++mt)
#pragma unroll
            for (int kb = 0; kb < 2; ++kb) {
                int row = mt * 16 + mrow;
                int hidx = (row * 64 + kb * 32 + kg * 8) ^ ((row & 7) << 3);
                a[mt][kb].u = *(const uint4*)&xsh[hidx];
            }
        const uint4* wp4 = (const uint4*)Wph;
        for (int t = wid; t < NT; t += 4) {
            union { uint4 u; f16x8 f; } b0, b1;
            b0.u = wp4[(t * 2 + 0) * 64 + lane];
            b1.u = wp4[(t * 2 + 1) * 64 + lane];
            float bias = bf[t * 16 + mrow];
            f32x4 acc0 = {0.f, 0.f, 0.f, 0.f}, acc1 = acc0, acc2 = acc0;
            acc0 = __builtin_amdgcn_mfma_f32_16x16x32_f16(a[0][0].f, b0.f, acc0, 0, 0, 0);
            acc0 = __builtin_amdgcn_mfma_f32_16x16x32_f16(a[0][1].f, b1.f, acc0, 0, 0, 0);
            acc1 = __builtin_amdgcn_mfma_f32_16x16x32_f16(a[1][0].f, b0.f, acc1, 0, 0, 0);
            acc1 = __builtin_amdgcn_mfma_f32_16x16x32_f16(a[1][1].f, b1.f, acc1, 0, 0, 0);
            acc2 = __builtin_amdgcn_mfma_f32_16x16x32_f16(a[2][0].f, b0.f, acc2, 0, 0, 0);
            acc2 = __builtin_amdgcn_mfma_f32_16x16x32_f16(a[2][1].f, b1.f, acc2, 0, 0, 0);
            int n = t * 16 + mrow;
#pragma unroll
            for (int mt = 0; mt < 3; ++mt) {
                f32x4 av = (mt == 0) ? acc0 : (mt == 1) ? acc1 : acc2;
#pragma unroll
                for (int reg = 0; reg < 4; ++reg) {
                    int m = mt * 16 + kg * 4 + reg;   // C/D row [m89]
                    float v = av[reg] + bias;
                    if (t < 8) {
                        int zr = m - 3;
                        if (zr >= 0 && zr < 32) zl[zr][n] = __float2half(v);
                    } else {
                        int xc = n - 128;
                        if (m < 35 && xc < 196) xdl[m][xc] = __float2half(v);
                    }
                }
            }
        }
    }
    __syncthreads();

    // ---- flush z tile (contiguous 8 KB, coalesced) ----
    {
        const uint4* zsrc = (const uint4*)&zl[0][0];
        uint4* zdst = (uint4*)(zbh + (size_t)rbase * D_INNER);
        zdst[tid]       = zsrc[tid];
        zdst[tid + 256] = zsrc[tid + 256];
    }
    __syncthreads();   // xsh/zl dead -> Xt/B16/Bt/C16 may be written

    // ---- conv + SiLU -> fp16 operand buffers; dt -> dtl ----
    if (tid < D_INNER) {
        // x-channels: Xt[p][i]
        int p = tid;
        float w0 = conv_w[p*4+0], w1 = conv_w[p*4+1];
        float w2 = conv_w[p*4+2], w3 = conv_w[p*4+3];
        float cb = conv_b[p];
        float vm1 = 0.f, vm2 = 0.f, vm3 = 0.f;
        if (c > 0) {
            vm1 = __half2float(xdl[2][p]);
            vm2 = __half2float(xdl[1][p]);
            vm3 = __half2float(xdl[0][p]);
        }
#pragma unroll
        for (int i = 0; i < CLEN; ++i) {
            float v0 = __half2float(xdl[i + 3][p]);
            float a = cb + v0 * w3 + vm1 * w2 + vm2 * w1 + vm3 * w0;
            float sv = a / (1.f + expf(-a));
            *(__half*)(smem + OXT + swz(p, i)) = __float2half(sv);
            vm3 = vm2; vm2 = vm1; vm1 = v0;
        }
    } else if (tid < D_INNER + D_STATE) {
        // B-channels: B16[j][n] and Bt[n][j]
        int n = tid - D_INNER;
        int ch = D_INNER + n;
        float w0 = conv_w[ch*4+0], w1 = conv_w[ch*4+1];
        float w2 = conv_w[ch*4+2], w3 = conv_w[ch*4+3];
        float cb = conv_b[ch];
        float vm1 = 0.f, vm2 = 0.f, vm3 = 0.f;
        if (c > 0) {
            vm1 = __half2float(xdl[2][ch]);
            vm2 = __half2float(xdl[1][ch]);
            vm3 = __half2float(xdl[0][ch]);
        }
#pragma unroll
        for (int i = 0; i < CLEN; ++i) {
            float v0 = __half2float(xdl[i + 3][ch]);
            float a = cb + v0 * w3 + vm1 * w2 + vm2 * w1 + vm3 * w0;
            __half hv = __float2half(a / (1.f + expf(-a)));
            *(__half*)(smem + OB16 + swz(i, n)) = hv;
            *(__half*)(smem + OBT  + swz(n, i)) = hv;
            vm3 = vm2; vm2 = vm1; vm1 = v0;
        }
    } else if (tid < D_XBC) {
        // C-channels: C16[i][n]
        int n = tid - (D_INNER + D_STATE);
        int ch = D_INNER + D_STATE + n;
        float w0 = conv_w[ch*4+0], w1 = conv_w[ch*4+1];
        float w2 = conv_w[ch*4+2], w3 = conv_w[ch*4+3];
        float cb = conv_b[ch];
        float vm1 = 0.f, vm2 = 0.f, vm3 = 0.f;
        if (c > 0) {
            vm1 = __half2float(xdl[2][ch]);
            vm2 = __half2float(xdl[1][ch]);
            vm3 = __half2float(xdl[0][ch]);
        }
#pragma unroll
        for (int i = 0; i < CLEN; ++i) {
            float v0 = __half2float(xdl[i + 3][ch]);
            float a = cb + v0 * w3 + vm1 * w2 + vm2 * w1 + vm3 * w0;
            *(__half*)(smem + OC16 + swz(i, n)) = __float2half(a / (1.f + expf(-a)));
            vm3 = vm2; vm2 = vm1; vm1 = v0;
        }
    } else {
        // dt: dtl[h][i] = softplus(v + dt_bias)
        int idx = tid - D_XBC;       // 0..63
        int h = idx >> 4;
        int i0 = idx & 15;
        float db = dt_bias[h];
        float* dtl = (float*)(smem + ODTL);
#pragma unroll
        for (int i = i0; i < CLEN; i += 16) {
            float v = __half2float(xdl[i + 3][192 + h]) + db;
            dtl[h * 32 + i] = (v > 20.f) ? v : log1pf(expf(v));
        }
    }
    __syncthreads();   // operands ready; xdl dead

    // ---- SSD scan: one head per warp ----
    int h = tid >> 6, l = tid & 63;
    int col = l & 15, kg = l >> 4;
    int li = l & 31;
    float nA = -expf(A_log[h]);
    float Dh = Dp[h];
    float* dtl = (float*)(smem + ODTL);
    float* lsl = (float*)(smem + OLSL);
    float* dcl = (float*)(smem + ODCL);
    __half2* wl2 = (__half2*)(smem + OWL2);

    // log-decay prefix (lanes 0..31; 32..63 duplicate harmlessly)
    {
        float dtv = dtl[h * 32 + li];
        float ls = dtv * nA;
#pragma unroll
        for (int d = 1; d < 32; d <<= 1) {
            float t = __shfl_up(ls, d, 32);
            if (li >= d) ls += t;
        }
        float cd = expf(ls);
        float lsE = __shfl(ls, 31, 32);
        float w = expf(lsE - ls) * dtv;
        float wn = __shfl_down(w, 1, 32);
        if (l < 32) {
            lsl[h * 32 + li] = ls;
            dcl[li * 4 + h] = cd;
            if ((li & 1) == 0) wl2[h * 16 + (li >> 1)] = __floats2half2_rn(w, wn);
            if (li == 31) Pbuf[(b * NHEADS + h) * NCHUNK + c] = cd;
        }
    }

    // G = C . B^T   (4 MFMA)
    f32x4 g[2][2];
    {
        union { uint4 u; f16x8 f; } ac[2], bb[2];
#pragma unroll
        for (int mt = 0; mt < 2; ++mt)
            ac[mt].u = *(const uint4*)(smem + OC16 + swz4(mt * 16 + col, kg));
#pragma unroll
        for (int nt = 0; nt < 2; ++nt)
            bb[nt].u = *(const uint4*)(smem + OB16 + swz4(nt * 16 + col, kg));
#pragma unroll
        for (int mt = 0; mt < 2; ++mt)
#pragma unroll
            for (int nt = 0; nt < 2; ++nt) {
                f32x4 z = {0.f, 0.f, 0.f, 0.f};
                g[mt][nt] = __builtin_amdgcn_mfma_f32_16x16x32_f16(ac[mt].f, bb[nt].f, z, 0, 0, 0);
            }
    }

    // M[i][j] = j<i ? G*exp(ls_i-ls_j)*dt_j : j==i ? G*dt_i + Dh : 0
    {
        const float* lslh = lsl + h * 32;
        const float* dtlh = dtl + h * 32;
#pragma unroll
        for (int nt = 0; nt < 2; ++nt) {
            int j = nt * 16 + col;
            float lsj = lslh[j], dtj = dtlh[j];
#pragma unroll
            for (int mt = 0; mt < 2; ++mt)
#pragma unroll
                for (int r = 0; r < 4; ++r) {
                    int i = mt * 16 + kg * 4 + r;
                    float mv = 0.f;
                    if (j < i)       mv = g[mt][nt][r] * expf(lslh[i] - lsj) * dtj;
                    else if (j == i) mv = g[mt][nt][r] * dtj + Dh;
                    *(__half*)(smem + OML + h * 2048 + swz(i, j)) = __float2half(mv);
                }
        }
    }

    // Y = M . X   (4 MFMA) -> pack fragment-order into Ypack
    {
        union { uint4 u; f16x8 f; } am[2], bx[2];
#pragma unroll
        for (int mt = 0; mt < 2; ++mt)
            am[mt].u = *(const uint4*)(smem + OML + h * 2048 + swz4(mt * 16 + col, kg));
#pragma unroll
        for (int nt = 0; nt < 2; ++nt)
            bx[nt].u = *(const uint4*)(smem + OXT + swz4(h * 32 + nt * 16 + col, kg));
        f32x4 y[2][2];
#pragma unroll
        for (int mt = 0; mt < 2; ++mt)
#pragma unroll
            for (int nt = 0; nt < 2; ++nt) {
                f32x4 z = {0.f, 0.f, 0.f, 0.f};
                y[mt][nt] = __builtin_amdgcn_mfma_f32_16x16x32_f16(am[mt].f, bx[nt].f, z, 0, 0, 0);
            }
#pragma unroll
        for (int mt = 0; mt < 2; ++mt) {
            __half2 hp[4];
            hp[0] = __floats2half2_rn(y[mt][0][0], y[mt][0][1]);
            hp[1] = __floats2half2_rn(y[mt][0][2], y[mt][0][3]);
            hp[2] = __floats2half2_rn(y[mt][1][0], y[mt][1][1]);
            hp[3] = __floats2half2_rn(y[mt][1][2], y[mt][1][3]);
            *(uint4*)(smem + OYP + mt * 4096 + (h * 64 + l) * 16) = *(uint4*)hp;
        }
    }

    // S = (w*X)^T-form . B  (4 MFMA) -> stage linear [h][p][n]
    {
        union { uint4 u; __half2 p[4]; f16x8 f; } aw[2], bt[2];
#pragma unroll
        for (int mt = 0; mt < 2; ++mt) {
            aw[mt].u = *(const uint4*)(smem + OXT + swz4(h * 32 + mt * 16 + col, kg));
            const __half2* wp = wl2 + h * 16 + kg * 4;
#pragma unroll
            for (int t = 0; t < 4; ++t) aw[mt].p[t] = __hmul2(aw[mt].p[t], wp[t]);
        }
#pragma unroll
        for (int nt = 0; nt < 2; ++nt)
            bt[nt].u = *(const uint4*)(smem + OBT + swz4(nt * 16 + col, kg));
        f32x4 s[2][2];
#pragma unroll
        for (int mt = 0; mt < 2; ++mt)
#pragma unroll
            for (int nt = 0; nt < 2; ++nt) {
                f32x4 z = {0.f, 0.f, 0.f, 0.f};
                s[mt][nt] = __builtin_amdgcn_mfma_f32_16x16x32_f16(aw[mt].f, bt[nt].f, z, 0, 0, 0);
            }
#pragma unroll
        for (int mt = 0; mt < 2; ++mt)
#pragma unroll
            for (int nt = 0; nt < 2; ++nt)
#pragma unroll
                for (int r = 0; r < 4; ++r) {
                    int p = mt * 16 + kg * 4 + r;
                    int n = nt * 16 + col;
                    *(__half*)(smem + OSL + h * 2048 + p * 64 + n * 2) =
                        __float2half(s[mt][nt][r]);
                }
    }
    __syncthreads();

    // ---- flushes (all coalesced) ----
    // S -> sbuf [p][n] per (bh,c)
#pragma unroll
    for (int k2 = 0; k2 < 2; ++k2) {
        int idx = tid + k2 * 256;          // 0..511 uint4
        int hh = idx >> 7, off = idx & 127;
        *(uint4*)(sbuf + (((size_t)(b * NHEADS + hh) * NCHUNK + c) << 10) + off * 8) =
            *(uint4*)(smem + OSL + hh * 2048 + off * 16);
    }
    // Ypack -> ybuf (chunk-packed: [mt][h][lane][nt][r])
#pragma unroll
    for (int k2 = 0; k2 < 2; ++k2) {
        int idx = tid + k2 * 256;          // 0..511 uint4
        int mt = idx >> 8, off = idx & 255;
        *(uint4*)(ybuf + (size_t)rbase * D_INNER + mt * 2048 + off * 8) =
            *(uint4*)(smem + OYP + mt * 4096 + off * 16);
    }
    // C16 -> Cbuf linear [i][n] (unswizzle)
    if (tid < 128) {
        int i = tid >> 2, blk = tid & 3;
        *(uint4*)(Cbuf + ((size_t)rbase + i) * D_STATE + blk * 8) =
            *(uint4*)(smem + OC16 + i * 64 + ((blk ^ (i & 3)) << 4));
    }
    // cumdec
    if (tid < 128) Dcum[(size_t)rbase * 4 + tid] = dcl[tid];
}

// ---------------------------------------------------------------------------
// Phase 2 (parallel): LDS-staged chunk-state combine. (unchanged)
__global__ __launch_bounds__(256) void scan_phase2_kernel(
        __half* __restrict__ sbuf, const float* __restrict__ Pbuf) {
    __shared__ unsigned sl[NCHUNK][128];   // 32 KB
    __shared__ float Pl[NCHUNK];
    int bh = blockIdx.x >> 2;
    int q  = blockIdx.x & 3;
    int tid = threadIdx.x;
    unsigned* s32 = (unsigned*)sbuf;
    size_t base = (size_t)bh * NCHUNK * 512 + (size_t)q * 128;
    if (tid < NCHUNK) Pl[tid] = Pbuf[bh * NCHUNK + tid];
    for (int k = tid; k < NCHUNK * 128; k += 256) {
        int c = k >> 7, j = k & 127;
        sl[c][j] = s32[base + (size_t)c * 512 + j];
    }
    __syncthreads();
    if (tid < 128) {
        float rx = 0.f, ry = 0.f;
        unsigned v = sl[0][tid];
#pragma unroll 8
        for (int c = 0; c < NCHUNK; ++c) {
            unsigned vn = (c + 1 < NCHUNK) ? sl[c + 1][tid] : 0u;
            float Pv = Pl[c];
            __half2 hv = *(__half2*)&v;
            float2 t = __half22float2(hv);
            __half2 hr = __floats2half2_rn(rx, ry);
            sl[c][tid] = *(unsigned*)&hr;
            rx = rx * Pv + t.x;
            ry = ry * Pv + t.y;
            v = vn;
        }
    }
    __syncthreads();
    for (int k = tid; k < NCHUNK * 128; k += 256) {
        int c = k >> 7, j = k & 127;
        s32[base + (size_t)c * 512 + j] = sl[c][j];
    }
}

// ---------------------------------------------------------------------------
// Phase 3 (half-chunk): y = y_u + cumdec*(C·seed), gate*silu(z), RMSNorm,
// head accumulation into out. ybuf is fragment-packed: sub sc&1 reads the
// mt=(sc&1) half (2048 contiguous halfs) and unpacks via the frag mapping.
__global__ __launch_bounds__(256) void scan_phase3_kernel(
        const __half* __restrict__ ybuf, const __half* __restrict__ Cbuf,
        const float* __restrict__ Dcum, const __half* __restrict__ zbh,
        const __half* __restrict__ sbuf, const float* __restrict__ norm_w,
        const float* __restrict__ Woc, float* __restrict__ out) {
    int b  = blockIdx.x >> 7;         // 128 subchunks per batch
    int sc = blockIdx.x & 127;        // subchunk index
    int c  = sc >> 1;                 // parent chunk (seed source)
    int tid = threadIdx.x;
    __shared__ float ylds[SUBL][D_INNER];   // 8 KB
    __shared__ float dcl[SUBL * 4];         // 256 B
    __shared__ float red[4][D_INNER];       // 2 KB
    __shared__ float snw[D_INNER];          // 512 B
    size_t rbase = (size_t)b * SEQ + (size_t)sc * SUBL;
    int h = tid >> 6, lane = tid & 63;
    int p = lane >> 1, n0 = (lane & 1) * 16;
    int bh = b * NHEADS + h;
    const uint4* sp = (const uint4*)(sbuf + ((size_t)bh * NCHUNK + c) * 1024) + lane * 2;
    uint4 u0 = sp[0], u1 = sp[1];
    // stage packed y_u -> fp32 LDS
    {
        const __half2* ysrc = (const __half2*)(
            ybuf + ((size_t)b * SEQ + (size_t)c * CLEN) * D_INNER + (size_t)(sc & 1) * 2048);
#pragma unroll
        for (int k = 0; k < 4; ++k) {
            int idx = tid + k * 256;          // 0..1023 half2
            float2 f = __half22float2(ysrc[idx]);
            int pos = idx * 2;                // [h(4)][lane(64)][nt(2)][r(4)]
            int hh = pos >> 9;
            int rem = pos & 511;
            int fl = rem >> 3;
            int rr = rem & 7;
            int nt = rr >> 2, r0 = rr & 3;    // r0 even
            int row = ((fl >> 4) << 2) + r0;
            int colc = hh * 32 + nt * 16 + (fl & 15);
            ylds[row][colc]     = f.x;
            ylds[row + 1][colc] = f.y;
        }
    }
    if (tid < SUBL * 4) dcl[tid] = Dcum[rbase * 4 + tid];
    float4 s0, s1, s2, s3;
    {
        const __half2* hp0 = (const __half2*)&u0;
        const __half2* hp1 = (const __half2*)&u1;
        float2 f;
        f = __half22float2(hp0[0]); s0.x = f.x; s0.y = f.y;
        f = __half22float2(hp0[1]); s0.z = f.x; s0.w = f.y;
        f = __half22float2(hp0[2]); s1.x = f.x; s1.y = f.y;
        f = __half22float2(hp0[3]); s1.z = f.x; s1.w = f.y;
        f = __half22float2(hp1[0]); s2.x = f.x; s2.y = f.y;
        f = __half22float2(hp1[1]); s2.z = f.x; s2.w = f.y;
        f = __half22float2(hp1[2]); s3.x = f.x; s3.y = f.y;
        f = __half22float2(hp1[3]); s3.z = f.x; s3.w = f.y;
    }
    __syncthreads();
#pragma unroll 4
    for (int i = 0; i < SUBL; ++i) {
        const uint4* cp = (const uint4*)(Cbuf + (rbase + i) * D_STATE + n0);
        uint4 ca = cp[0], cb = cp[1];
        const __half2* cha = (const __half2*)&ca;
        const __half2* chb = (const __half2*)&cb;
        float2 f0 = __half22float2(cha[0]);
        float2 f1 = __half22float2(cha[1]);
        float2 f2 = __half22float2(cha[2]);
        float2 f3 = __half22float2(cha[3]);
        float2 f4 = __half22float2(chb[0]);
        float2 f5 = __half22float2(chb[1]);
        float2 f6 = __half22float2(chb[2]);
        float2 f7 = __half22float2(chb[3]);
        float part = s0.x*f0.x + s0.y*f0.y + s0.z*f1.x + s0.w*f1.y
                   + s1.x*f2.x + s1.y*f2.y + s1.z*f3.x + s1.w*f3.y
                   + s2.x*f4.x + s2.y*f4.y + s2.z*f5.x + s2.w*f5.y
                   + s3.x*f6.x + s3.y*f6.y + s3.z*f7.x + s3.w*f7.y;
        part += __shfl_xor(part, 1);
        if ((lane & 1) == 0)
            ylds[i][h * HEADDIM + p] += dcl[i * 4 + h] * part;
    }
    __syncthreads();
    float acc0 = 0.f, acc1 = 0.f;
    for (int r = h; r < SUBL; r += 4) {
        size_t bl = rbase + r;
        float2 yv = *(const float2*)(&ylds[r][lane * 2]);
        float2 zv = __half22float2(*((const __half2*)(zbh + bl * D_INNER) + lane));
        float g0 = yv.x * (zv.x / (1.f + expf(-zv.x)));
        float g1 = yv.y * (zv.y / (1.f + expf(-zv.y)));
        float sq = g0 * g0 + g1 * g1;
#pragma unroll
        for (int m = 1; m < 64; m <<= 1) sq += __shfl_xor(sq, m);
        float rms = 1.0f / sqrtf(sq * (1.f / 128.f) + 1e-5f);
        acc0 += g0 * rms;
        acc1 += g1 * rms;
    }
    red[h][lane * 2]     = acc0;
    red[h][lane * 2 + 1] = acc1;
    __syncthreads();
    if (tid < D_INNER)
        snw[tid] = (red[0][tid] + red[1][tid] + red[2][tid] + red[3][tid])
                   * norm_w[tid];
    __syncthreads();
    if (tid < OUT_DIM) {
        float acc = 0.f;
#pragma unroll 8
        for (int i = 0; i < D_INNER; ++i)
            acc += snw[i] * Woc[i * OUT_DIM + tid];
        atomicAdd(&out[b * OUT_DIM + tid], acc * (1.f / (float)SEQ));
    }
}

// ---------------------------------------------------------------------------
extern "C" void kernel_launch(void* const* d_in, const int* in_sizes, int n_in,
                              void* d_out, int out_size, void* d_ws, size_t ws_size,
                              hipStream_t stream) {
    const float* x       = (const float*)d_in[0];
    const float* W_lin   = (const float*)d_in[1];
    const float* b_lin   = (const float*)d_in[2];
    const float* W_in    = (const float*)d_in[3];
    const float* conv_w  = (const float*)d_in[4];
    const float* conv_b  = (const float*)d_in[5];
    const float* dt_bias = (const float*)d_in[6];
    const float* A_log   = (const float*)d_in[7];
    const float* Dp      = (const float*)d_in[8];
    const float* norm_w  = (const float*)d_in[9];
    const float* W_out   = (const float*)d_in[10];
    const float* W_cls   = (const float*)d_in[11];
    const float* b_cls   = (const float*)d_in[12];
    float* out = (float*)d_out;

    float* ws = (float*)d_ws;
    __half* Wph  = (__half*)(ws + OFF_WP);
    float* bf    = ws + OFF_BF;
    float* Woc   = ws + OFF_WOC;
    float* Pbuf  = ws + OFF_P;
    float* Dcum  = ws + OFF_DC;
    __half* zbh  = (__half*)(ws + OFF_ZB);
    __half* Cbh  = (__half*)(ws + OFF_CB);
    __half* ybh  = (__half*)(ws + OFF_YB);
    __half* sbuf = (__half*)(ws + OFF_SB);

    // 1) fused weight precompute
    int nfw = 64 * 336 + D_IN_PROJ + D_INNER * OUT_DIM + BATCH * OUT_DIM;
    fuse_w_kernel<<<(nfw + 255) / 256, 256, 0, stream>>>(
        W_lin, b_lin, W_in, W_out, W_cls, Wph, bf, Woc, b_cls, out);

    // 2) mega kernel: MFMA inproj + conv + SSD MFMA scan per chunk
    mega1_kernel<<<BATCH * NCHUNK, 256, 0, stream>>>(
        x, Wph, bf, conv_w, conv_b, dt_bias, A_log, Dp,
        zbh, sbuf, Pbuf, ybh, Cbh, Dcum);

    // 3) parallel LDS-staged chunk-state combine
    scan_phase2_kernel<<<256, 256, 0, stream>>>(sbuf, Pbuf);

    // 4) half-chunk correction + gating + RMSNorm + head accumulation
    scan_phase3_kernel<<<BATCH * 128, 256, 0, stream>>>(
        ybh, Cbh, Dcum, zbh, sbuf, norm_w, Woc, out);
}

// Round 8
// 143.171 us; speedup vs baseline: 2.1691x; 1.0065x over previous
//
#include <hip/hip_runtime.h>
#include <hip/hip_fp16.h>
#include <cmath>

// Problem constants
#define BATCH   16
#define SEQ     2048
#define IN_DIM  57
#define D_MODEL 64
#define HEADDIM 32
#define D_STATE 32
#define OUT_DIM 6
#define D_INNER 128
#define NHEADS  4
#define D_CONV  4
#define D_XBC   192          // D_INNER + 2*D_STATE
#define D_IN_PROJ 324        // 2*D_INNER + 2*D_STATE + NHEADS
#define BL      (BATCH*SEQ)  // 32768

// Chunked scan config
#define NCHUNK  64
#define CLEN    (SEQ / NCHUNK)   // 32
#define SUBL    16               // phase3 rows per block (half chunk)

// MFMA inproj geometry: M=48 (3x16, rows 0..34 valid), K=64 (57 valid),
// N=336 (21x16, cols 0..323 valid).
#define NT      21               // n-tiles

typedef _Float16 f16x8 __attribute__((ext_vector_type(8)));
typedef _Float16 f16x2 __attribute__((ext_vector_type(2)));
typedef float    f32x4 __attribute__((ext_vector_type(4)));

// mega1 LDS map (bytes). Lifetime phases:
//  [inproj]  xsh 0..6144 (dead after A-frag load), zl 6144..14336,
//            xdT 16128..30240 (196 ch x 36 rows, transposed)
//  [conv]    Xt 0..8192, B16 8192..10240, Bt 10240..12288, C16 12288..14336,
//            dtl/lsl/wl2/dcl 14336..16128; reads xdT
//  [ssd]     Ml 16128..24320 (xdT dead), Ypack 24320..32512; S reuses Ml
#define OXT   0
#define OB16  8192
#define OBT   10240
#define OC16  12288
#define ODTL  14336
#define OLSL  14848
#define OWL2  15360
#define ODCL  15616
#define OXDT  16128
#define OML   16128
#define OSL   16128
#define OYP   24320
#define SMEM_SZ 32512
#define XDT_STRIDE 36            // halfs per channel row (72 B, 8B-aligned)

// Workspace layout (floats). zb/cb/yb/sbuf/wp hold fp16.
#define OFF_WP   ((size_t)0)                        // 10752 floats (fp16 packed W)
#define OFF_BF   ((size_t)10752)                    // 324 -> pad 336
#define OFF_WOC  ((size_t)11088)                    // 768
#define OFF_P    ((size_t)11856)                    // 4096
#define OFF_DC   ((size_t)15952)                    // BL*4 = 131072
#define OFF_ZB   ((size_t)147024)                   // BL*128 halfs
#define OFF_CB   (OFF_ZB + (size_t)BL*64)           // BL*32 halfs
#define OFF_YB   (OFF_CB + (size_t)BL*16)           // BL*128 halfs (packed frag order)
#define OFF_SB   (OFF_YB + (size_t)BL*64)           // 64*64*1024 halfs

// Swizzled half-address within a [rows][32]-half fp16 buffer (64 B rows,
// 16B-block XOR by row&3 -> aligned b128 reads, <=4-way bank conflicts).
__device__ __forceinline__ int swz(int row, int j) {
    return row * 64 + (((j >> 3) ^ (row & 3)) << 4) + ((j & 7) << 1);
}
__device__ __forceinline__ int swz4(int row, int kg) {   // uint4 read addr
    return row * 64 + ((kg ^ (row & 3)) << 4);
}

// ---------------------------------------------------------------------------
// Kernel 1: packed fp16 Wp = (W_lin@W_in) in MFMA B-fragment layout;
// bf = b_lin@W_in ; W_oc = W_out@W_cls ; out = b_cls.
__global__ void fuse_w_kernel(const float* __restrict__ W_lin,
                              const float* __restrict__ b_lin,
                              const float* __restrict__ W_in,
                              const float* __restrict__ W_out,
                              const float* __restrict__ W_cls,
                              __half* __restrict__ Wph, float* __restrict__ bf,
                              float* __restrict__ Woc,
                              const float* __restrict__ b_cls,
                              float* __restrict__ out) {
    int idx = blockIdx.x * 256 + threadIdx.x;
    if (idx < 64 * 336) {
        int k = idx / 336;
        int n = idx - k * 336;
        float acc = 0.f;
        if (k < IN_DIM && n < D_IN_PROJ) {
#pragma unroll 8
            for (int m = 0; m < D_MODEL; ++m)
                acc += W_lin[k * D_MODEL + m] * W_in[m * D_IN_PROJ + n];
        }
        int t = n >> 4, nl = n & 15;
        int kb = k >> 5, kr = k & 31;
        size_t pidx = (((size_t)(t * 2 + kb) * 64) + (kr >> 3) * 16 + nl) * 8 + (kr & 7);
        Wph[pidx] = __float2half(acc);
    } else if (idx < 64 * 336 + D_IN_PROJ) {
        int n = idx - 64 * 336;
        float acc = 0.f;
#pragma unroll 8
        for (int m = 0; m < D_MODEL; ++m)
            acc += b_lin[m] * W_in[m * D_IN_PROJ + n];
        bf[n] = acc;
    } else if (idx < 64 * 336 + D_IN_PROJ + D_INNER * OUT_DIM) {
        int idx2 = idx - (64 * 336 + D_IN_PROJ);
        int i = idx2 / OUT_DIM;
        int o = idx2 - i * OUT_DIM;
        float acc = 0.f;
#pragma unroll 8
        for (int j = 0; j < D_MODEL; ++j)
            acc += W_out[i * D_MODEL + j] * W_cls[j * OUT_DIM + o];
        Woc[i * OUT_DIM + o] = acc;
    } else if (idx < 64 * 336 + D_IN_PROJ + D_INNER * OUT_DIM + BATCH * OUT_DIM) {
        int idx3 = idx - (64 * 336 + D_IN_PROJ + D_INNER * OUT_DIM);
        out[idx3] = b_cls[idx3 % OUT_DIM];
    }
}

// ---------------------------------------------------------------------------
// Mega kernel: MFMA in-projection (xd written TRANSPOSED via 8B fragment
// stores) -> conv/SiLU/dt (stride-1 reads) -> SSD chunked scan on MFMA.
// 32.5 KB LDS -> 5 blocks/CU.
__global__ __launch_bounds__(256) void mega1_kernel(
        const float* __restrict__ x,
        const __half* __restrict__ Wph, const float* __restrict__ bf,
        const float* __restrict__ conv_w, const float* __restrict__ conv_b,
        const float* __restrict__ dt_bias, const float* __restrict__ A_log,
        const float* __restrict__ Dp,
        __half* __restrict__ zbh,
        __half* __restrict__ sbuf, float* __restrict__ Pbuf,
        __half* __restrict__ ybuf, __half* __restrict__ Cbuf,
        float* __restrict__ Dcum) {
    __shared__ __align__(16) char smem[SMEM_SZ];
    __half* xsh        = (__half*)smem;                    // 48x64 fp16 [inproj]
    __half (*zl)[128]  = (__half (*)[128])(smem + 6144);   // 32x128 fp16 [inproj]
    __half* xdT        = (__half*)(smem + OXDT);           // [196][36] transposed

    int b = blockIdx.x >> 6;          // NCHUNK=64
    int c = blockIdx.x & (NCHUNK - 1);
    int tid = threadIdx.x;
    long rbase = (long)b * SEQ + (long)c * CLEN;

    // ---- stage x rows rbase-3 .. rbase+31 as fp16, XOR-swizzled ----
    for (int i = tid; i < 48 * 64; i += 256) {
        int r = i >> 6, k = i & 63;
        float v = 0.f;
        if (r < 35 && k < IN_DIM && (c > 0 || r >= 3))
            v = x[(rbase - 3 + r) * IN_DIM + k];
        xsh[i ^ ((r & 7) << 3)] = __float2half(v);
    }
    __syncthreads();

    // ---- MFMA in-projection: y[48][336] = x[48][64] @ Wf[64][336] + bf ----
    {
        int wid = tid >> 6, lane = tid & 63;
        int mrow = lane & 15, kg = lane >> 4;
        union { uint4 u; f16x8 f; } a[3][2];
#pragma unroll
        for (int mt = 0; mt < 3; ++mt)
#pragma unroll
            for (int kb = 0; kb < 2; ++kb) {
                int row = mt * 16 + mrow;
                int hidx = (row * 64 + kb * 32 + kg * 8) ^ ((row & 7) << 3);
                a[mt][kb].u = *(const uint4*)&xsh[hidx];
            }
        const uint4* wp4 = (const uint4*)Wph;
        for (int t = wid; t < NT; t += 4) {
            union { uint4 u; f16x8 f; } b0, b1;
            b0.u = wp4[(t * 2 + 0) * 64 + lane];
            b1.u = wp4[(t * 2 + 1) * 64 + lane];
            float bias = bf[t * 16 + mrow];
            f32x4 acc0 = {0.f, 0.f, 0.f, 0.f}, acc1 = acc0, acc2 = acc0;
            acc0 = __builtin_amdgcn_mfma_f32_16x16x32_f16(a[0][0].f, b0.f, acc0, 0, 0, 0);
            acc0 = __builtin_amdgcn_mfma_f32_16x16x32_f16(a[0][1].f, b1.f, acc0, 0, 0, 0);
            acc1 = __builtin_amdgcn_mfma_f32_16x16x32_f16(a[1][0].f, b0.f, acc1, 0, 0, 0);
            acc1 = __builtin_amdgcn_mfma_f32_16x16x32_f16(a[1][1].f, b1.f, acc1, 0, 0, 0);
            acc2 = __builtin_amdgcn_mfma_f32_16x16x32_f16(a[2][0].f, b0.f, acc2, 0, 0, 0);
            acc2 = __builtin_amdgcn_mfma_f32_16x16x32_f16(a[2][1].f, b1.f, acc2, 0, 0, 0);
            int n = t * 16 + mrow;
            if (t < 8) {
                // z tile: scalar scatter (rows shifted by halo-3)
#pragma unroll
                for (int mt = 0; mt < 3; ++mt) {
                    f32x4 av = (mt == 0) ? acc0 : (mt == 1) ? acc1 : acc2;
#pragma unroll
                    for (int reg = 0; reg < 4; ++reg) {
                        int m = mt * 16 + kg * 4 + reg;
                        int zr = m - 3;
                        if (zr >= 0 && zr < 32)
                            zl[zr][n] = __float2half(av[reg] + bias);
                    }
                }
            } else {
                // xd tile: transposed fragment store (one 8B write per mt)
                int xc = n - 128;
                if (xc < 196) {
#pragma unroll
                    for (int mt = 0; mt < 3; ++mt) {
                        if (mt == 2 && kg != 0) continue;  // rows >=36 invalid
                        f32x4 av = (mt == 0) ? acc0 : (mt == 1) ? acc1 : acc2;
                        __half hv[4];
#pragma unroll
                        for (int reg = 0; reg < 4; ++reg)
                            hv[reg] = __float2half(av[reg] + bias);
                        int m0 = mt * 16 + kg * 4;
                        *(uint2*)&xdT[xc * XDT_STRIDE + m0] = *(uint2*)hv;
                    }
                }
            }
        }
    }
    __syncthreads();

    // ---- flush z tile (contiguous 8 KB, coalesced) ----
    {
        const uint4* zsrc = (const uint4*)&zl[0][0];
        uint4* zdst = (uint4*)(zbh + (size_t)rbase * D_INNER);
        zdst[tid]       = zsrc[tid];
        zdst[tid + 256] = zsrc[tid + 256];
    }
    __syncthreads();   // xsh/zl dead -> Xt/B16/Bt/C16 may be written

    // ---- conv + SiLU -> fp16 operand buffers; dt -> dtl ----
    if (tid < D_INNER) {
        // x-channels: Xt[p][i]
        int p = tid;
        float w0 = conv_w[p*4+0], w1 = conv_w[p*4+1];
        float w2 = conv_w[p*4+2], w3 = conv_w[p*4+3];
        float cb = conv_b[p];
        const __half* src = xdT + p * XDT_STRIDE;
        float vm1 = 0.f, vm2 = 0.f, vm3 = 0.f;
        if (c > 0) {
            vm1 = __half2float(src[2]);
            vm2 = __half2float(src[1]);
            vm3 = __half2float(src[0]);
        }
#pragma unroll
        for (int i = 0; i < CLEN; ++i) {
            float v0 = __half2float(src[i + 3]);
            float a = cb + v0 * w3 + vm1 * w2 + vm2 * w1 + vm3 * w0;
            float sv = a / (1.f + expf(-a));
            *(__half*)(smem + OXT + swz(p, i)) = __float2half(sv);
            vm3 = vm2; vm2 = vm1; vm1 = v0;
        }
    } else if (tid < D_INNER + D_STATE) {
        // B-channels: B16[j][n] and Bt[n][j]
        int n = tid - D_INNER;
        int ch = D_INNER + n;
        float w0 = conv_w[ch*4+0], w1 = conv_w[ch*4+1];
        float w2 = conv_w[ch*4+2], w3 = conv_w[ch*4+3];
        float cb = conv_b[ch];
        const __half* src = xdT + ch * XDT_STRIDE;
        float vm1 = 0.f, vm2 = 0.f, vm3 = 0.f;
        if (c > 0) {
            vm1 = __half2float(src[2]);
            vm2 = __half2float(src[1]);
            vm3 = __half2float(src[0]);
        }
#pragma unroll
        for (int i = 0; i < CLEN; ++i) {
            float v0 = __half2float(src[i + 3]);
            float a = cb + v0 * w3 + vm1 * w2 + vm2 * w1 + vm3 * w0;
            __half hv = __float2half(a / (1.f + expf(-a)));
            *(__half*)(smem + OB16 + swz(i, n)) = hv;
            *(__half*)(smem + OBT  + swz(n, i)) = hv;
            vm3 = vm2; vm2 = vm1; vm1 = v0;
        }
    } else if (tid < D_XBC) {
        // C-channels: C16[i][n]
        int n = tid - (D_INNER + D_STATE);
        int ch = D_INNER + D_STATE + n;
        float w0 = conv_w[ch*4+0], w1 = conv_w[ch*4+1];
        float w2 = conv_w[ch*4+2], w3 = conv_w[ch*4+3];
        float cb = conv_b[ch];
        const __half* src = xdT + ch * XDT_STRIDE;
        float vm1 = 0.f, vm2 = 0.f, vm3 = 0.f;
        if (c > 0) {
            vm1 = __half2float(src[2]);
            vm2 = __half2float(src[1]);
            vm3 = __half2float(src[0]);
        }
#pragma unroll
        for (int i = 0; i < CLEN; ++i) {
            float v0 = __half2float(src[i + 3]);
            float a = cb + v0 * w3 + vm1 * w2 + vm2 * w1 + vm3 * w0;
            *(__half*)(smem + OC16 + swz(i, n)) = __float2half(a / (1.f + expf(-a)));
            vm3 = vm2; vm2 = vm1; vm1 = v0;
        }
    } else {
        // dt: dtl[h][i] = softplus(v + dt_bias)
        int idx = tid - D_XBC;       // 0..63
        int h = idx >> 4;
        int i0 = idx & 15;
        float db = dt_bias[h];
        float* dtl = (float*)(smem + ODTL);
        const __half* src = xdT + (192 + h) * XDT_STRIDE;
#pragma unroll
        for (int i = i0; i < CLEN; i += 16) {
            float v = __half2float(src[i + 3]) + db;
            dtl[h * 32 + i] = (v > 20.f) ? v : log1pf(expf(v));
        }
    }
    __syncthreads();   // operands ready; xdT dead

    // ---- SSD scan: one head per warp ----
    int h = tid >> 6, l = tid & 63;
    int col = l & 15, kg = l >> 4;
    int li = l & 31;
    float nA = -expf(A_log[h]);
    float Dh = Dp[h];
    float* dtl = (float*)(smem + ODTL);
    float* lsl = (float*)(smem + OLSL);
    float* dcl = (float*)(smem + ODCL);
    __half2* wl2 = (__half2*)(smem + OWL2);

    // log-decay prefix (lanes 0..31; 32..63 duplicate harmlessly)
    {
        float dtv = dtl[h * 32 + li];
        float ls = dtv * nA;
#pragma unroll
        for (int d = 1; d < 32; d <<= 1) {
            float t = __shfl_up(ls, d, 32);
            if (li >= d) ls += t;
        }
        float cd = expf(ls);
        float lsE = __shfl(ls, 31, 32);
        float w = expf(lsE - ls) * dtv;
        float wn = __shfl_down(w, 1, 32);
        if (l < 32) {
            lsl[h * 32 + li] = ls;
            dcl[li * 4 + h] = cd;
            if ((li & 1) == 0) wl2[h * 16 + (li >> 1)] = __floats2half2_rn(w, wn);
            if (li == 31) Pbuf[(b * NHEADS + h) * NCHUNK + c] = cd;
        }
    }

    // G = C . B^T   (4 MFMA)
    f32x4 g[2][2];
    {
        union { uint4 u; f16x8 f; } ac[2], bb[2];
#pragma unroll
        for (int mt = 0; mt < 2; ++mt)
            ac[mt].u = *(const uint4*)(smem + OC16 + swz4(mt * 16 + col, kg));
#pragma unroll
        for (int nt = 0; nt < 2; ++nt)
            bb[nt].u = *(const uint4*)(smem + OB16 + swz4(nt * 16 + col, kg));
#pragma unroll
        for (int mt = 0; mt < 2; ++mt)
#pragma unroll
            for (int nt = 0; nt < 2; ++nt) {
                f32x4 z = {0.f, 0.f, 0.f, 0.f};
                g[mt][nt] = __builtin_amdgcn_mfma_f32_16x16x32_f16(ac[mt].f, bb[nt].f, z, 0, 0, 0);
            }
    }

    // M[i][j] = j<i ? G*exp(ls_i-ls_j)*dt_j : j==i ? G*dt_i + Dh : 0
    {
        const float* lslh = lsl + h * 32;
        const float* dtlh = dtl + h * 32;
#pragma unroll
        for (int nt = 0; nt < 2; ++nt) {
            int j = nt * 16 + col;
            float lsj = lslh[j], dtj = dtlh[j];
#pragma unroll
            for (int mt = 0; mt < 2; ++mt)
#pragma unroll
                for (int r = 0; r < 4; ++r) {
                    int i = mt * 16 + kg * 4 + r;
                    float mv = 0.f;
                    if (j < i)       mv = g[mt][nt][r] * expf(lslh[i] - lsj) * dtj;
                    else if (j == i) mv = g[mt][nt][r] * dtj + Dh;
                    *(__half*)(smem + OML + h * 2048 + swz(i, j)) = __float2half(mv);
                }
        }
    }

    // Y = M . X   (4 MFMA) -> pack fragment-order into Ypack
    {
        union { uint4 u; f16x8 f; } am[2], bx[2];
#pragma unroll
        for (int mt = 0; mt < 2; ++mt)
            am[mt].u = *(const uint4*)(smem + OML + h * 2048 + swz4(mt * 16 + col, kg));
#pragma unroll
        for (int nt = 0; nt < 2; ++nt)
            bx[nt].u = *(const uint4*)(smem + OXT + swz4(h * 32 + nt * 16 + col, kg));
        f32x4 y[2][2];
#pragma unroll
        for (int mt = 0; mt < 2; ++mt)
#pragma unroll
            for (int nt = 0; nt < 2; ++nt) {
                f32x4 z = {0.f, 0.f, 0.f, 0.f};
                y[mt][nt] = __builtin_amdgcn_mfma_f32_16x16x32_f16(am[mt].f, bx[nt].f, z, 0, 0, 0);
            }
#pragma unroll
        for (int mt = 0; mt < 2; ++mt) {
            __half2 hp[4];
            hp[0] = __floats2half2_rn(y[mt][0][0], y[mt][0][1]);
            hp[1] = __floats2half2_rn(y[mt][0][2], y[mt][0][3]);
            hp[2] = __floats2half2_rn(y[mt][1][0], y[mt][1][1]);
            hp[3] = __floats2half2_rn(y[mt][1][2], y[mt][1][3]);
            *(uint4*)(smem + OYP + mt * 4096 + (h * 64 + l) * 16) = *(uint4*)hp;
        }
    }

    // S = (w*X)^T-form . B  (4 MFMA) -> stage linear [h][p][n]
    {
        union { uint4 u; __half2 p[4]; f16x8 f; } aw[2], bt[2];
#pragma unroll
        for (int mt = 0; mt < 2; ++mt) {
            aw[mt].u = *(const uint4*)(smem + OXT + swz4(h * 32 + mt * 16 + col, kg));
            const __half2* wp = wl2 + h * 16 + kg * 4;
#pragma unroll
            for (int t = 0; t < 4; ++t) aw[mt].p[t] = __hmul2(aw[mt].p[t], wp[t]);
        }
#pragma unroll
        for (int nt = 0; nt < 2; ++nt)
            bt[nt].u = *(const uint4*)(smem + OBT + swz4(nt * 16 + col, kg));
        f32x4 s[2][2];
#pragma unroll
        for (int mt = 0; mt < 2; ++mt)
#pragma unroll
            for (int nt = 0; nt < 2; ++nt) {
                f32x4 z = {0.f, 0.f, 0.f, 0.f};
                s[mt][nt] = __builtin_amdgcn_mfma_f32_16x16x32_f16(aw[mt].f, bt[nt].f, z, 0, 0, 0);
            }
#pragma unroll
        for (int mt = 0; mt < 2; ++mt)
#pragma unroll
            for (int nt = 0; nt < 2; ++nt)
#pragma unroll
                for (int r = 0; r < 4; ++r) {
                    int p = mt * 16 + kg * 4 + r;
                    int n = nt * 16 + col;
                    *(__half*)(smem + OSL + h * 2048 + p * 64 + n * 2) =
                        __float2half(s[mt][nt][r]);
                }
    }
    __syncthreads();

    // ---- flushes (all coalesced) ----
#pragma unroll
    for (int k2 = 0; k2 < 2; ++k2) {
        int idx = tid + k2 * 256;          // 0..511 uint4
        int hh = idx >> 7, off = idx & 127;
        *(uint4*)(sbuf + (((size_t)(b * NHEADS + hh) * NCHUNK + c) << 10) + off * 8) =
            *(uint4*)(smem + OSL + hh * 2048 + off * 16);
    }
#pragma unroll
    for (int k2 = 0; k2 < 2; ++k2) {
        int idx = tid + k2 * 256;          // 0..511 uint4
        int mt = idx >> 8, off = idx & 255;
        *(uint4*)(ybuf + (size_t)rbase * D_INNER + mt * 2048 + off * 8) =
            *(uint4*)(smem + OYP + mt * 4096 + off * 16);
    }
    if (tid < 128) {
        int i = tid >> 2, blk = tid & 3;
        *(uint4*)(Cbuf + ((size_t)rbase + i) * D_STATE + blk * 8) =
            *(uint4*)(smem + OC16 + i * 64 + ((blk ^ (i & 3)) << 4));
    }
    if (tid < 128) Dcum[(size_t)rbase * 4 + tid] = dcl[tid];
}

// ---------------------------------------------------------------------------
// Phase 2 (parallel): LDS-staged chunk-state combine. (unchanged)
__global__ __launch_bounds__(256) void scan_phase2_kernel(
        __half* __restrict__ sbuf, const float* __restrict__ Pbuf) {
    __shared__ unsigned sl[NCHUNK][128];   // 32 KB
    __shared__ float Pl[NCHUNK];
    int bh = blockIdx.x >> 2;
    int q  = blockIdx.x & 3;
    int tid = threadIdx.x;
    unsigned* s32 = (unsigned*)sbuf;
    size_t base = (size_t)bh * NCHUNK * 512 + (size_t)q * 128;
    if (tid < NCHUNK) Pl[tid] = Pbuf[bh * NCHUNK + tid];
    for (int k = tid; k < NCHUNK * 128; k += 256) {
        int c = k >> 7, j = k & 127;
        sl[c][j] = s32[base + (size_t)c * 512 + j];
    }
    __syncthreads();
    if (tid < 128) {
        float rx = 0.f, ry = 0.f;
        unsigned v = sl[0][tid];
#pragma unroll 8
        for (int c = 0; c < NCHUNK; ++c) {
            unsigned vn = (c + 1 < NCHUNK) ? sl[c + 1][tid] : 0u;
            float Pv = Pl[c];
            __half2 hv = *(__half2*)&v;
            float2 t = __half22float2(hv);
            __half2 hr = __floats2half2_rn(rx, ry);
            sl[c][tid] = *(unsigned*)&hr;
            rx = rx * Pv + t.x;
            ry = ry * Pv + t.y;
            v = vn;
        }
    }
    __syncthreads();
    for (int k = tid; k < NCHUNK * 128; k += 256) {
        int c = k >> 7, j = k & 127;
        s32[base + (size_t)c * 512 + j] = sl[c][j];
    }
}

// ---------------------------------------------------------------------------
// Phase 3 (half-chunk): y = y_u + cumdec*(C·seed) via fdot2, gate*silu(z),
// RMSNorm, head accumulation into out.
__global__ __launch_bounds__(256) void scan_phase3_kernel(
        const __half* __restrict__ ybuf, const __half* __restrict__ Cbuf,
        const float* __restrict__ Dcum, const __half* __restrict__ zbh,
        const __half* __restrict__ sbuf, const float* __restrict__ norm_w,
        const float* __restrict__ Woc, float* __restrict__ out) {
    int b  = blockIdx.x >> 7;         // 128 subchunks per batch
    int sc = blockIdx.x & 127;        // subchunk index
    int c  = sc >> 1;                 // parent chunk (seed source)
    int tid = threadIdx.x;
    __shared__ float ylds[SUBL][D_INNER];   // 8 KB
    __shared__ float dcl[SUBL * 4];         // 256 B
    __shared__ float red[4][D_INNER];       // 2 KB
    __shared__ float snw[D_INNER];          // 512 B
    size_t rbase = (size_t)b * SEQ + (size_t)sc * SUBL;
    int h = tid >> 6, lane = tid & 63;
    int p = lane >> 1, n0 = (lane & 1) * 16;
    int bh = b * NHEADS + h;
    // seed load (kept packed as 8x half2 for fdot2)
    const uint4* sp = (const uint4*)(sbuf + ((size_t)bh * NCHUNK + c) * 1024) + lane * 2;
    union { uint4 u[2]; f16x2 h2[8]; } sd;
    sd.u[0] = sp[0];
    sd.u[1] = sp[1];
    // stage packed y_u -> fp32 LDS
    {
        const __half2* ysrc = (const __half2*)(
            ybuf + ((size_t)b * SEQ + (size_t)c * CLEN) * D_INNER + (size_t)(sc & 1) * 2048);
#pragma unroll
        for (int k = 0; k < 4; ++k) {
            int idx = tid + k * 256;          // 0..1023 half2
            float2 f = __half22float2(ysrc[idx]);
            int pos = idx * 2;                // [h(4)][lane(64)][nt(2)][r(4)]
            int hh = pos >> 9;
            int rem = pos & 511;
            int fl = rem >> 3;
            int rr = rem & 7;
            int nt = rr >> 2, r0 = rr & 3;    // r0 even
            int row = ((fl >> 4) << 2) + r0;
            int colc = hh * 32 + nt * 16 + (fl & 15);
            ylds[row][colc]     = f.x;
            ylds[row + 1][colc] = f.y;
        }
    }
    if (tid < SUBL * 4) dcl[tid] = Dcum[rbase * 4 + tid];
    __syncthreads();
#pragma unroll 4
    for (int i = 0; i < SUBL; ++i) {
        const uint4* cp = (const uint4*)(Cbuf + (rbase + i) * D_STATE + n0);
        union { uint4 u[2]; f16x2 h2[8]; } cv;
        cv.u[0] = cp[0];
        cv.u[1] = cp[1];
        float part = 0.f;
#pragma unroll
        for (int k = 0; k < 8; ++k)
            part = __builtin_amdgcn_fdot2(cv.h2[k], sd.h2[k], part, false);
        part += __shfl_xor(part, 1);
        if ((lane & 1) == 0)
            ylds[i][h * HEADDIM + p] += dcl[i * 4 + h] * part;
    }
    __syncthreads();
    float acc0 = 0.f, acc1 = 0.f;
    for (int r = h; r < SUBL; r += 4) {
        size_t bl = rbase + r;
        float2 yv = *(const float2*)(&ylds[r][lane * 2]);
        float2 zv = __half22float2(*((const __half2*)(zbh + bl * D_INNER) + lane));
        float g0 = yv.x * (zv.x / (1.f + expf(-zv.x)));
        float g1 = yv.y * (zv.y / (1.f + expf(-zv.y)));
        float sq = g0 * g0 + g1 * g1;
#pragma unroll
        for (int m = 1; m < 64; m <<= 1) sq += __shfl_xor(sq, m);
        float rms = 1.0f / sqrtf(sq * (1.f / 128.f) + 1e-5f);
        acc0 += g0 * rms;
        acc1 += g1 * rms;
    }
    red[h][lane * 2]     = acc0;
    red[h][lane * 2 + 1] = acc1;
    __syncthreads();
    if (tid < D_INNER)
        snw[tid] = (red[0][tid] + red[1][tid] + red[2][tid] + red[3][tid])
                   * norm_w[tid];
    __syncthreads();
    if (tid < OUT_DIM) {
        float acc = 0.f;
#pragma unroll 8
        for (int i = 0; i < D_INNER; ++i)
            acc += snw[i] * Woc[i * OUT_DIM + tid];
        atomicAdd(&out[b * OUT_DIM + tid], acc * (1.f / (float)SEQ));
    }
}

// ---------------------------------------------------------------------------
extern "C" void kernel_launch(void* const* d_in, const int* in_sizes, int n_in,
                              void* d_out, int out_size, void* d_ws, size_t ws_size,
                              hipStream_t stream) {
    const float* x       = (const float*)d_in[0];
    const float* W_lin   = (const float*)d_in[1];
    const float* b_lin   = (const float*)d_in[2];
    const float* W_in    = (const float*)d_in[3];
    const float* conv_w  = (const float*)d_in[4];
    const float* conv_b  = (const float*)d_in[5];
    const float* dt_bias = (const float*)d_in[6];
    const float* A_log   = (const float*)d_in[7];
    const float* Dp      = (const float*)d_in[8];
    const float* norm_w  = (const float*)d_in[9];
    const float* W_out   = (const float*)d_in[10];
    const float* W_cls   = (const float*)d_in[11];
    const float* b_cls   = (const float*)d_in[12];
    float* out = (float*)d_out;

    float* ws = (float*)d_ws;
    __half* Wph  = (__half*)(ws + OFF_WP);
    float* bf    = ws + OFF_BF;
    float* Woc   = ws + OFF_WOC;
    float* Pbuf  = ws + OFF_P;
    float* Dcum  = ws + OFF_DC;
    __half* zbh  = (__half*)(ws + OFF_ZB);
    __half* Cbh  = (__half*)(ws + OFF_CB);
    __half* ybh  = (__half*)(ws + OFF_YB);
    __half* sbuf = (__half*)(ws + OFF_SB);

    // 1) fused weight precompute
    int nfw = 64 * 336 + D_IN_PROJ + D_INNER * OUT_DIM + BATCH * OUT_DIM;
    fuse_w_kernel<<<(nfw + 255) / 256, 256, 0, stream>>>(
        W_lin, b_lin, W_in, W_out, W_cls, Wph, bf, Woc, b_cls, out);

    // 2) mega kernel: MFMA inproj + conv + SSD MFMA scan per chunk
    mega1_kernel<<<BATCH * NCHUNK, 256, 0, stream>>>(
        x, Wph, bf, conv_w, conv_b, dt_bias, A_log, Dp,
        zbh, sbuf, Pbuf, ybh, Cbh, Dcum);

    // 3) parallel LDS-staged chunk-state combine
    scan_phase2_kernel<<<256, 256, 0, stream>>>(sbuf, Pbuf);

    // 4) half-chunk correction + gating + RMSNorm + head accumulation
    scan_phase3_kernel<<<BATCH * 128, 256, 0, stream>>>(
        ybh, Cbh, Dcum, zbh, sbuf, norm_w, Woc, out);
}